// Round 1
// baseline (47627.142 us; speedup 1.0000x reference)
//
#include <hip/hip_runtime.h>

typedef _Float16 f16;
typedef __attribute__((ext_vector_type(8))) _Float16 half8;
typedef __attribute__((ext_vector_type(2))) _Float16 half2v;
typedef __attribute__((ext_vector_type(4))) float f32x4;
typedef __attribute__((ext_vector_type(4))) unsigned int u32x4;

#define NBLK 256
#define TSTEPS 1024

// ---- workspace layout (bytes) ----
static const size_t OFF_WP   = 0;           // f16 [32 ns][4 nt][26 ks][64 lane][8]  = 3,407,872
static const size_t OFF_BIAS = 3407872;     // f32 [2048] gate-interleaved            = 8,192
static const size_t OFF_EMBP = 3416064;     // f16 [1024 t][8 bg][32 kc][16 bl][8]    = 67,108,864
static const size_t OFF_V    = 70524928;    // f32 [1024 t][128 b][64 m]              = 33,554,432
static const size_t OFF_XPRH = 104079360;   // f16 [2 par][8 bg][72 kc][16 bl][8]     = 294,912
static const size_t OFF_MEM  = 104374272;   // f32 [128 b][128 n][64 m]               = 4,194,304
static const size_t OFF_BAR  = 108568576;   // u32 barrier counter
static const size_t WS_NEED  = 108568704;

// ---------------- prologue kernels ----------------

// pack gates weights into B-fragment order, rows interleaved as n' = j*4 + gate
__global__ void marnn_packw(const float* __restrict__ w_ih, const float* __restrict__ w_hh,
                            const float* __restrict__ b_ih, const float* __restrict__ b_hh,
                            f16* __restrict__ WP, float* __restrict__ biasP) {
  int idx = blockIdx.x * 256 + threadIdx.x;
  if (idx < 2048) {
    int j = idx >> 2, g = idx & 3, rg = g * 512 + j;
    biasP[idx] = b_ih[rg] + b_hh[rg];
  }
  if (idx >= 1703936) return;
  int e = idx & 7, l = (idx >> 3) & 63;
  int q = idx >> 9;
  int ks = q % 26; int q2 = q / 26; int nt = q2 & 3, ns = q2 >> 2;
  int n = ns * 64 + nt * 16 + (l & 15);
  int k = ks * 32 + (l >> 4) * 8 + e;
  int j2 = n >> 2, g2 = n & 3, rg2 = g2 * 512 + j2;
  float v = (k < 320) ? w_ih[(size_t)rg2 * 320 + k] : w_hh[(size_t)rg2 * 512 + (k - 320)];
  WP[idx] = (f16)v;
}

// pack embeddings into A-fragment layout (f16)
__global__ void marnn_packemb(const float* __restrict__ embs, f16* __restrict__ embsP) {
  long idx = (long)blockIdx.x * 256 + threadIdx.x;
  if (idx >= (long)1024 * 128 * 256) return;
  int e = idx & 7, bl = (idx >> 3) & 15, kc = (idx >> 7) & 31, bg = (idx >> 12) & 7;
  long t = idx >> 15;
  embsP[idx] = (f16)embs[((t * 128) + bg * 16 + bl) * 256 + kc * 8 + e];
}

// precompute v[t][b][m] = emb[t,b] @ W_wv^T + b_wv  (f32, all t)
__global__ void marnn_vpre(const float* __restrict__ embs, const float* __restrict__ W_wv,
                           const float* __restrict__ b_wv, float* __restrict__ V) {
  long idx = (long)blockIdx.x * 256 + threadIdx.x;
  if (idx >= (long)1024 * 128 * 64) return;
  int m = idx & 63; int b = (idx >> 6) & 127; long t = idx >> 13;
  const float* e = embs + (t * 128 + b) * 256;
  const float* w = W_wv + m * 256;
  float acc = b_wv[m];
  #pragma unroll 4
  for (int k = 0; k < 256; k += 4) {
    f32x4 e4 = *(const f32x4*)(e + k);
    f32x4 w4 = *(const f32x4*)(w + k);
    acc += e4[0]*w4[0] + e4[1]*w4[1] + e4[2]*w4[2] + e4[3]*w4[3];
  }
  V[idx] = acc;
}

// init packed state buffer: r-sections (both parities) = r0, h-section(par 0) = h0
__global__ void marnn_init(const float* __restrict__ h0, const float* __restrict__ r0,
                           f16* __restrict__ XPRH) {
  int idx = blockIdx.x * 256 + threadIdx.x;
  if (idx >= 147456) return;
  int e = idx & 7; int q = idx >> 7; int kcidx = q % 72;
  float v = (kcidx < 8) ? r0[kcidx * 8 + e] : h0[(kcidx - 8) * 8 + e];
  XPRH[idx] = (f16)v;
}

// ---------------- main persistent kernel ----------------

struct __align__(16) MarnnSMem {
  f16  whead[128 * 512];   // 131072 B, rotate-swizzled rows
  char xl[26624];          // X fragments [104 kc][16 bl][8] f16
  char un[4096];           // phase A: gatebuf [16][64] f32 | phase M: logits/p/vred/vsec
};

__device__ __forceinline__ float marnn_dot8(half8 a, half8 b, float acc) {
#if __has_builtin(__builtin_amdgcn_fdot2)
  half2v a0 = {a[0],a[1]}, a1 = {a[2],a[3]}, a2 = {a[4],a[5]}, a3 = {a[6],a[7]};
  half2v b0 = {b[0],b[1]}, b1 = {b[2],b[3]}, b2 = {b[4],b[5]}, b3 = {b[6],b[7]};
  acc = __builtin_amdgcn_fdot2(a0, b0, acc, false);
  acc = __builtin_amdgcn_fdot2(a1, b1, acc, false);
  acc = __builtin_amdgcn_fdot2(a2, b2, acc, false);
  acc = __builtin_amdgcn_fdot2(a3, b3, acc, false);
#else
  #pragma unroll
  for (int e = 0; e < 8; ++e) acc += (float)a[e] * (float)b[e];
#endif
  return acc;
}

__device__ __forceinline__ void marnn_gbar(unsigned* cnt, unsigned target) {
  __syncthreads();
  if (threadIdx.x == 0) {
    __threadfence();
    __hip_atomic_fetch_add(cnt, 1u, __ATOMIC_RELAXED, __HIP_MEMORY_SCOPE_AGENT);
    while (__hip_atomic_load(cnt, __ATOMIC_RELAXED, __HIP_MEMORY_SCOPE_AGENT) < target)
      __builtin_amdgcn_s_sleep(2);
    __threadfence();
  }
  __syncthreads();
}

__global__ __launch_bounds__(256, 1)
void marnn_main(const int* __restrict__ ilen_p, const float* __restrict__ c0,
                const float* __restrict__ r0,
                const float* __restrict__ W_wa, const float* __restrict__ b_wa,
                const float* __restrict__ W_ra, const float* __restrict__ b_ra,
                float* __restrict__ out, char* __restrict__ ws) {
  __shared__ MarnnSMem sm;

  const f16*   WP    = (const f16*)(ws + OFF_WP);
  const float* biasP = (const float*)(ws + OFF_BIAS);
  const f16*   embsP = (const f16*)(ws + OFF_EMBP);
  const float* Vbuf  = (const float*)(ws + OFF_V);
  f16*         XPRH  = (f16*)(ws + OFF_XPRH);
  float*       MEMB  = (float*)(ws + OFF_MEM);
  unsigned*    BAR   = (unsigned*)(ws + OFF_BAR);

  const int blk = blockIdx.x, tid = threadIdx.x;
  const int wav = tid >> 6, lane = tid & 63;
  const int bg = blk >> 5, ns = blk & 31;      // batch-group (16 b) x n-slice (64 rows)
  const int ilen = ilen_p[0];

  // persistent B-fragments: wave 'wav' owns n-tile ns*64 + wav*16
  half8 bfr[26];
  {
    const f16* wpb = WP + (((size_t)(ns * 4 + wav)) * 26) * 512 + lane * 8;
    #pragma unroll
    for (int ks = 0; ks < 26; ++ks) bfr[ks] = *(const half8*)(wpb + ks * 512);
  }

  // load memory-head weight matrix to LDS (f16, rotate-swizzled rows: slot' = (slot+n)&63)
  auto loadWhead = [&](const float* Wsrc) {
    for (int i = tid; i < 8192; i += 256) {
      int n = i >> 6, slot = i & 63;
      const float* s = Wsrc + n * 512 + slot * 8;
      f32x4 a = *(const f32x4*)(s), b2 = *(const f32x4*)(s + 4);
      half8 hv;
      hv[0]=(f16)a[0]; hv[1]=(f16)a[1]; hv[2]=(f16)a[2]; hv[3]=(f16)a[3];
      hv[4]=(f16)b2[0]; hv[5]=(f16)b2[1]; hv[6]=(f16)b2[2]; hv[7]=(f16)b2[3];
      *(half8*)((char*)sm.whead + (n << 10) + (((slot + n) & 63) << 4)) = hv;
    }
  };
  if (blk < 128) loadWhead(ilen > 0 ? W_wa : W_ra);

  // stage X fragments (emb section + h section) into LDS
  auto stageX = [&](int tsrc, int parsrc) {
    const u32x4* s0 = (const u32x4*)(embsP + (((size_t)tsrc * 8) + bg) * 4096);
    u32x4* d0 = (u32x4*)sm.xl;
    d0[tid * 2]     = s0[tid * 2];
    d0[tid * 2 + 1] = s0[tid * 2 + 1];
    const u32x4* s1 = (const u32x4*)(XPRH + (((size_t)parsrc * 8 + bg) * 72 + 8) * 128);
    u32x4* d1 = (u32x4*)(sm.xl + 10240);
    #pragma unroll
    for (int i = 0; i < 4; ++i) d1[tid * 4 + i] = s1[tid * 4 + i];
  };
  stageX(0, 0);
  __syncthreads();

  // activation thread ownership: (b_local, j_local) fixed across steps; c in register
  const int b_l = tid >> 4, jj = tid & 15;
  const int jg = ns * 16 + jj;                 // j in [0,512)
  float c = c0[jg];
  const f32x4 bias4 = *(const f32x4*)(biasP + ns * 64 + jj * 4);

  for (int t = 0; t < TSTEPS; ++t) {
    const int par = t & 1, nxt = par ^ 1;
    const bool iswrite = (t < ilen);

    // ---------------- phase A: gates GEMM + activations ----------------
    const f16* rbase = XPRH + (((size_t)par * 8 + bg) * 72) * 128 + (lane >> 4) * 128 + (lane & 15) * 8;
    half8 rf0 = *(const half8*)(rbase);
    half8 rf1 = *(const half8*)(rbase + 4 * 128);
    f32x4 acc = {0.f, 0.f, 0.f, 0.f};
    const char* xb = sm.xl + (lane >> 4) * 256 + (lane & 15) * 16;
    #pragma unroll
    for (int ks = 0; ks < 26; ++ks) {
      half8 af = (ks == 8) ? rf0 : (ks == 9) ? rf1 : *(const half8*)(xb + ks * 1024);
      acc = __builtin_amdgcn_mfma_f32_16x16x32_f16(af, bfr[ks], acc, 0, 0, 0);
    }
    {
      float* gatebuf = (float*)sm.un;  // [16 b][64 n-local]
      #pragma unroll
      for (int r = 0; r < 4; ++r)
        gatebuf[((lane >> 4) * 4 + r) * 64 + wav * 16 + (lane & 15)] = acc[r];
    }
    __syncthreads();
    {
      const float* gatebuf = (const float*)sm.un;
      f32x4 g4 = *(const f32x4*)(gatebuf + b_l * 64 + jj * 4);
      float gi = g4[0] + bias4[0], gf = g4[1] + bias4[1];
      float gg = g4[2] + bias4[2], go = g4[3] + bias4[3];
      float si = 1.f / (1.f + __expf(-gi));
      float sf = 1.f / (1.f + __expf(-gf));
      float so = 1.f / (1.f + __expf(-go));
      c = sf * c + si * tanhf(gg);
      float h = so * tanhf(c);
      int b = bg * 16 + b_l;
      out[(size_t)t * 73728 + b * 576 + jg] = h;
      XPRH[(((size_t)nxt * 8 + bg) * 72 + 8 + (jg >> 3)) * 128 + b_l * 8 + (jj & 7)] = (f16)h;
    }
    marnn_gbar(BAR, (unsigned)(2 * t + 1) * NBLK);

    // ---------------- phase M: memory head (blocks 0..127, one b each) ----------------
    if (blk < 128) {
      const int b = blk;
      if (t == ilen) { loadWhead(W_ra); __syncthreads(); }
      float* logits = (float*)sm.un;
      float* pbuf   = (float*)(sm.un + 512);
      float* vred   = (float*)(sm.un + 1024);
      float* vsec   = (float*)(sm.un + 1536);
      const int n = wav * 32 + (lane & 31);
      const int kh = lane >> 5;
      const char* wrow = (const char*)sm.whead + (n << 10);
      const f16* hsrc = XPRH + (((size_t)nxt * 8 + (b >> 4)) * 72) * 128 + (b & 15) * 8;
      float av = 0.f;
      #pragma unroll 8
      for (int i = 0; i < 32; ++i) {
        half8 wv = *(const half8*)(wrow + (((kh * 32 + i + n) & 63) << 4));
        half8 hv = *(const half8*)(hsrc + (8 + kh * 32 + i) * 128);
        av = marnn_dot8(wv, hv, av);
      }
      av += __shfl_xor(av, 32, 64);
      if (lane < 32) logits[n] = av + (iswrite ? b_wa[n] : b_ra[n]);
      if (iswrite && wav == 1 && lane < 16)
        *(f32x4*)(vsec + lane * 4) = *(const f32x4*)(Vbuf + ((size_t)t * 128 + b) * 64 + lane * 4);
      __syncthreads();
      if (wav == 0) {
        float l0 = logits[lane], l1 = logits[lane + 64];
        float mx = fmaxf(l0, l1);
        #pragma unroll
        for (int off = 32; off > 0; off >>= 1) mx = fmaxf(mx, __shfl_xor(mx, off, 64));
        float e0 = __expf(l0 - mx), e1 = __expf(l1 - mx);
        float s = e0 + e1;
        #pragma unroll
        for (int off = 32; off > 0; off >>= 1) s += __shfl_xor(s, off, 64);
        float inv = 1.f / s;
        pbuf[lane] = e0 * inv; pbuf[lane + 64] = e1 * inv;
      }
      __syncthreads();
      if (iswrite) {
        float p = pbuf[tid >> 1];
        float* mrow = MEMB + (((size_t)b) * 128 + (tid >> 1)) * 64 + (tid & 1) * 32;
        const float* vv = vsec + (tid & 1) * 32;
        #pragma unroll
        for (int i2 = 0; i2 < 32; i2 += 4) {
          f32x4 mm = *(f32x4*)(mrow + i2);
          f32x4 v4 = *(const f32x4*)(vv + i2);
          mm = mm + p * v4;
          *(f32x4*)(mrow + i2) = mm;
        }
        if (tid < 64) out[(size_t)t * 73728 + b * 576 + 512 + tid] = r0[tid];
      } else {
        if (wav < 2) {
          const float* mcol = MEMB + (((size_t)b) * 128 + wav * 64) * 64 + lane;
          float a2 = 0.f;
          #pragma unroll 8
          for (int n2 = 0; n2 < 64; ++n2) a2 = fmaf(pbuf[wav * 64 + n2], mcol[n2 * 64], a2);
          vred[wav * 64 + lane] = a2;
        }
        __syncthreads();
        if (tid < 64) {
          float rv = vred[tid] + vred[64 + tid];
          out[(size_t)t * 73728 + b * 576 + 512 + tid] = rv;
          XPRH[(((size_t)nxt * 8 + (b >> 4)) * 72 + (tid >> 3)) * 128 + (b & 15) * 8 + (tid & 7)] = (f16)rv;
        }
      }
    }
    // overlapped staging for step t+1 (h_t visible since bar1; emb static)
    if (t + 1 < TSTEPS) stageX(t + 1, nxt);
    marnn_gbar(BAR, (unsigned)(2 * t + 2) * NBLK);
  }
}

// ---------------- host ----------------

extern "C" void kernel_launch(void* const* d_in, const int* in_sizes, int n_in,
                              void* d_out, int out_size, void* d_ws, size_t ws_size,
                              hipStream_t stream) {
  const float* embs = (const float*)d_in[0];
  const int*   ilen = (const int*)d_in[1];
  const float* w_ih = (const float*)d_in[2];
  const float* w_hh = (const float*)d_in[3];
  const float* b_ih = (const float*)d_in[4];
  const float* b_hh = (const float*)d_in[5];
  const float* h0   = (const float*)d_in[6];
  const float* c0   = (const float*)d_in[7];
  const float* r0   = (const float*)d_in[8];
  const float* W_wa = (const float*)d_in[9];
  const float* b_wa = (const float*)d_in[10];
  const float* W_wv = (const float*)d_in[11];
  const float* b_wv = (const float*)d_in[12];
  const float* W_ra = (const float*)d_in[13];
  const float* b_ra = (const float*)d_in[14];
  float* out = (float*)d_out;
  char* ws = (char*)d_ws;
  if (ws_size < WS_NEED) return;  // insufficient scratch: fail cleanly

  hipMemsetAsync(ws + OFF_MEM, 0, 4194304, stream);
  hipMemsetAsync(ws + OFF_BAR, 0, 128, stream);
  marnn_packw<<<6656, 256, 0, stream>>>(w_ih, w_hh, b_ih, b_hh,
                                        (f16*)(ws + OFF_WP), (float*)(ws + OFF_BIAS));
  marnn_packemb<<<131072, 256, 0, stream>>>(embs, (f16*)(ws + OFF_EMBP));
  marnn_vpre<<<32768, 256, 0, stream>>>(embs, W_wv, b_wv, (float*)(ws + OFF_V));
  marnn_init<<<576, 256, 0, stream>>>(h0, r0, (f16*)(ws + OFF_XPRH));
  marnn_main<<<256, 256, 0, stream>>>(ilen, c0, r0, W_wa, b_wa, W_ra, b_ra, out, ws);
}

// Round 2
// 35223.203 us; speedup vs baseline: 1.3522x; 1.3522x over previous
//
#include <hip/hip_runtime.h>

typedef _Float16 f16;
typedef __attribute__((ext_vector_type(8))) _Float16 half8;
typedef __attribute__((ext_vector_type(2))) _Float16 half2v;
typedef __attribute__((ext_vector_type(4))) float f32x4;
typedef __attribute__((ext_vector_type(4))) unsigned int u32x4;

#define NBLK 256
#define TSTEPS 1024

// ---- workspace layout (bytes) ----
static const size_t OFF_WP   = 0;           // f16 [32 ns][4 nt][26 ks][64 lane][8]  = 3,407,872
static const size_t OFF_BIAS = 3407872;     // f32 [2048] gate-interleaved            = 8,192
static const size_t OFF_EMBP = 3416064;     // f16 [1024 t][8 bg][32 kc][16 bl][8]    = 67,108,864
static const size_t OFF_V    = 70524928;    // f32 [1024 t][128 b][64 m]              = 33,554,432
static const size_t OFF_XPRH = 104079360;   // f16 [2 par][8 bg][72 kc][16 bl][8]     = 294,912
static const size_t OFF_MEM  = 104374272;   // f32 [128 b][128 n][64 m]               = 4,194,304
static const size_t OFF_BAR  = 108568576;   // u32 flags[256] (one per block)
static const size_t WS_NEED  = 108569600;

// ---------------- prologue kernels ----------------

// pack gates weights into B-fragment order, rows interleaved as n' = j*4 + gate
__global__ void marnn_packw(const float* __restrict__ w_ih, const float* __restrict__ w_hh,
                            const float* __restrict__ b_ih, const float* __restrict__ b_hh,
                            f16* __restrict__ WP, float* __restrict__ biasP) {
  int idx = blockIdx.x * 256 + threadIdx.x;
  if (idx < 2048) {
    int j = idx >> 2, g = idx & 3, rg = g * 512 + j;
    biasP[idx] = b_ih[rg] + b_hh[rg];
  }
  if (idx >= 1703936) return;
  int e = idx & 7, l = (idx >> 3) & 63;
  int q = idx >> 9;
  int ks = q % 26; int q2 = q / 26; int nt = q2 & 3, ns = q2 >> 2;
  int n = ns * 64 + nt * 16 + (l & 15);
  int k = ks * 32 + (l >> 4) * 8 + e;
  int j2 = n >> 2, g2 = n & 3, rg2 = g2 * 512 + j2;
  float v = (k < 320) ? w_ih[(size_t)rg2 * 320 + k] : w_hh[(size_t)rg2 * 512 + (k - 320)];
  WP[idx] = (f16)v;
}

// pack embeddings into A-fragment layout (f16)
__global__ void marnn_packemb(const float* __restrict__ embs, f16* __restrict__ embsP) {
  long idx = (long)blockIdx.x * 256 + threadIdx.x;
  if (idx >= (long)1024 * 128 * 256) return;
  int e = idx & 7, bl = (idx >> 3) & 15, kc = (idx >> 7) & 31, bg = (idx >> 12) & 7;
  long t = idx >> 15;
  embsP[idx] = (f16)embs[((t * 128) + bg * 16 + bl) * 256 + kc * 8 + e];
}

// precompute v[t][b][m] = emb[t,b] @ W_wv^T + b_wv  (f32, all t)
__global__ void marnn_vpre(const float* __restrict__ embs, const float* __restrict__ W_wv,
                           const float* __restrict__ b_wv, float* __restrict__ V) {
  long idx = (long)blockIdx.x * 256 + threadIdx.x;
  if (idx >= (long)1024 * 128 * 64) return;
  int m = idx & 63; int b = (idx >> 6) & 127; long t = idx >> 13;
  const float* e = embs + (t * 128 + b) * 256;
  const float* w = W_wv + m * 256;
  float acc = b_wv[m];
  #pragma unroll 4
  for (int k = 0; k < 256; k += 4) {
    f32x4 e4 = *(const f32x4*)(e + k);
    f32x4 w4 = *(const f32x4*)(w + k);
    acc += e4[0]*w4[0] + e4[1]*w4[1] + e4[2]*w4[2] + e4[3]*w4[3];
  }
  V[idx] = acc;
}

// init packed state buffer: r-sections (both parities) = r0, h-section(par 0) = h0
__global__ void marnn_init(const float* __restrict__ h0, const float* __restrict__ r0,
                           f16* __restrict__ XPRH) {
  int idx = blockIdx.x * 256 + threadIdx.x;
  if (idx >= 147456) return;
  int e = idx & 7; int q = idx >> 7; int kcidx = q % 72;
  float v = (kcidx < 8) ? r0[kcidx * 8 + e] : h0[(kcidx - 8) * 8 + e];
  XPRH[idx] = (f16)v;
}

// ---------------- main persistent kernel ----------------

struct __align__(16) MarnnSMem {
  f16  whead[128 * 512];   // 131072 B, rotate-swizzled rows
  char xl[26624];          // X fragments [104 kc][16 bl][8] f16
  char un[4096];           // phase A: gatebuf [16][64] f32 | phase M: logits/p/vred/vsec
};

__device__ __forceinline__ float marnn_dot8(half8 a, half8 b, float acc) {
#if __has_builtin(__builtin_amdgcn_fdot2)
  half2v a0 = {a[0],a[1]}, a1 = {a[2],a[3]}, a2 = {a[4],a[5]}, a3 = {a[6],a[7]};
  half2v b0 = {b[0],b[1]}, b1 = {b[2],b[3]}, b2 = {b[4],b[5]}, b3 = {b[6],b[7]};
  acc = __builtin_amdgcn_fdot2(a0, b0, acc, false);
  acc = __builtin_amdgcn_fdot2(a1, b1, acc, false);
  acc = __builtin_amdgcn_fdot2(a2, b2, acc, false);
  acc = __builtin_amdgcn_fdot2(a3, b3, acc, false);
#else
  #pragma unroll
  for (int e = 0; e < 8; ++e) acc += (float)a[e] * (float)b[e];
#endif
  return acc;
}

// contention-free grid barrier: per-block flag store + flat 256-flag poll by wave 0
__device__ __forceinline__ void marnn_fbar(unsigned* flags, int blk, unsigned target) {
  __syncthreads();
  if (threadIdx.x == 0) {
    __threadfence();
    __hip_atomic_store(flags + blk, target, __ATOMIC_RELAXED, __HIP_MEMORY_SCOPE_AGENT);
  }
  if (threadIdx.x < 64) {
    const int l4 = threadIdx.x * 4;
    for (;;) {
      unsigned v0 = __hip_atomic_load(flags + l4 + 0, __ATOMIC_RELAXED, __HIP_MEMORY_SCOPE_AGENT);
      unsigned v1 = __hip_atomic_load(flags + l4 + 1, __ATOMIC_RELAXED, __HIP_MEMORY_SCOPE_AGENT);
      unsigned v2 = __hip_atomic_load(flags + l4 + 2, __ATOMIC_RELAXED, __HIP_MEMORY_SCOPE_AGENT);
      unsigned v3 = __hip_atomic_load(flags + l4 + 3, __ATOMIC_RELAXED, __HIP_MEMORY_SCOPE_AGENT);
      int ok = (v0 >= target) && (v1 >= target) && (v2 >= target) && (v3 >= target);
      if (__all(ok)) break;
      __builtin_amdgcn_s_sleep(2);
    }
    __threadfence();
  }
  __syncthreads();
}

__global__ __launch_bounds__(256, 1)
void marnn_main(const int* __restrict__ ilen_p, const float* __restrict__ c0,
                const float* __restrict__ r0,
                const float* __restrict__ W_wa, const float* __restrict__ b_wa,
                const float* __restrict__ W_ra, const float* __restrict__ b_ra,
                float* __restrict__ out, char* __restrict__ ws) {
  __shared__ MarnnSMem sm;

  const f16*   WP    = (const f16*)(ws + OFF_WP);
  const float* biasP = (const float*)(ws + OFF_BIAS);
  const f16*   embsP = (const f16*)(ws + OFF_EMBP);
  const float* Vbuf  = (const float*)(ws + OFF_V);
  f16*         XPRH  = (f16*)(ws + OFF_XPRH);
  float*       MEMB  = (float*)(ws + OFF_MEM);
  unsigned*    FLAGS = (unsigned*)(ws + OFF_BAR);

  const int blk = blockIdx.x, tid = threadIdx.x;
  const int wav = tid >> 6, lane = tid & 63;
  const int bg = blk >> 5, ns = blk & 31;      // batch-group (16 b) x n-slice (64 rows)
  const int ilen = ilen_p[0];

  // persistent B-fragments: wave 'wav' owns n-tile ns*64 + wav*16
  half8 bfr[26];
  {
    const f16* wpb = WP + (((size_t)(ns * 4 + wav)) * 26) * 512 + lane * 8;
    #pragma unroll
    for (int ks = 0; ks < 26; ++ks) bfr[ks] = *(const half8*)(wpb + ks * 512);
  }

  // load memory-head weight matrix to LDS (f16, rotate-swizzled rows: slot' = (slot+n)&63)
  auto loadWhead = [&](const float* Wsrc) {
    for (int i = tid; i < 8192; i += 256) {
      int n = i >> 6, slot = i & 63;
      const float* s = Wsrc + n * 512 + slot * 8;
      f32x4 a = *(const f32x4*)(s), b2 = *(const f32x4*)(s + 4);
      half8 hv;
      hv[0]=(f16)a[0]; hv[1]=(f16)a[1]; hv[2]=(f16)a[2]; hv[3]=(f16)a[3];
      hv[4]=(f16)b2[0]; hv[5]=(f16)b2[1]; hv[6]=(f16)b2[2]; hv[7]=(f16)b2[3];
      *(half8*)((char*)sm.whead + (n << 10) + (((slot + n) & 63) << 4)) = hv;
    }
  };
  if (blk < 128) loadWhead(ilen > 0 ? W_wa : W_ra);

  // initial X stage (t=0, parity 0)
  {
    const u32x4* s0 = (const u32x4*)(embsP + ((size_t)0 * 8 + bg) * 4096);
    u32x4* d0 = (u32x4*)sm.xl;
    d0[tid * 2]     = s0[tid * 2];
    d0[tid * 2 + 1] = s0[tid * 2 + 1];
    const u32x4* s1 = (const u32x4*)(XPRH + (((size_t)0 * 8 + bg) * 72 + 8) * 128);
    u32x4* d1 = (u32x4*)(sm.xl + 10240);
    #pragma unroll
    for (int i = 0; i < 4; ++i) d1[tid * 4 + i] = s1[tid * 4 + i];
  }
  __syncthreads();

  // activation thread ownership: (b_local, j_local) fixed across steps; c in register
  const int b_l = tid >> 4, jj = tid & 15;
  const int jg = ns * 16 + jj;                 // j in [0,512)
  float c = c0[jg];
  const f32x4 bias4 = *(const f32x4*)(biasP + ns * 64 + jj * 4);
  const float r0v = (tid < 64) ? r0[tid] : 0.f;

  unsigned ep = 0;

  for (int t = 0; t < TSTEPS; ++t) {
    const int par = t & 1, nxt = par ^ 1;
    const bool iswrite = (t < ilen);

    // ---------------- phase A: gates GEMM + activations ----------------
    const f16* rbase = XPRH + (((size_t)par * 8 + bg) * 72) * 128 + (lane >> 4) * 128 + (lane & 15) * 8;
    half8 rf0 = *(const half8*)(rbase);
    half8 rf1 = *(const half8*)(rbase + 4 * 128);
    f32x4 acc = {0.f, 0.f, 0.f, 0.f};
    const char* xb = sm.xl + (lane >> 4) * 256 + (lane & 15) * 16;
    #pragma unroll
    for (int ks = 0; ks < 26; ++ks) {
      half8 af = (ks == 8) ? rf0 : (ks == 9) ? rf1 : *(const half8*)(xb + ks * 1024);
      acc = __builtin_amdgcn_mfma_f32_16x16x32_f16(af, bfr[ks], acc, 0, 0, 0);
    }
    {
      float* gatebuf = (float*)sm.un;  // [16 b][64 n-local]
      #pragma unroll
      for (int r = 0; r < 4; ++r)
        gatebuf[((lane >> 4) * 4 + r) * 64 + wav * 16 + (lane & 15)] = acc[r];
    }
    __syncthreads();
    {
      const float* gatebuf = (const float*)sm.un;
      f32x4 g4 = *(const f32x4*)(gatebuf + b_l * 64 + jj * 4);
      float gi = g4[0] + bias4[0], gf = g4[1] + bias4[1];
      float gg = g4[2] + bias4[2], go = g4[3] + bias4[3];
      float si = 1.f / (1.f + __expf(-gi));
      float sf = 1.f / (1.f + __expf(-gf));
      float so = 1.f / (1.f + __expf(-go));
      c = sf * c + si * tanhf(gg);
      float h = so * tanhf(c);
      int b = bg * 16 + b_l;
      out[(size_t)t * 73728 + b * 576 + jg] = h;
      XPRH[(((size_t)nxt * 8 + bg) * 72 + 8 + (jg >> 3)) * 128 + b_l * 8 + (jj & 7)] = (f16)h;
    }
    marnn_fbar(FLAGS, blk, ++ep);   // h_{t+1} visible grid-wide

    // ---- stage loads for step t+1 (issue early; stores after M) ----
    const bool dostage = (t + 1 < TSTEPS);
    u32x4 sa0, sa1, sb0, sb1, sb2, sb3;
    if (dostage) {
      const u32x4* s0 = (const u32x4*)(embsP + (((size_t)(t + 1) * 8) + bg) * 4096);
      sa0 = s0[tid * 2]; sa1 = s0[tid * 2 + 1];
      const u32x4* s1 = (const u32x4*)(XPRH + (((size_t)nxt * 8 + bg) * 72 + 8) * 128);
      sb0 = s1[tid * 4 + 0]; sb1 = s1[tid * 4 + 1];
      sb2 = s1[tid * 4 + 2]; sb3 = s1[tid * 4 + 3];
    }

    // ---------------- phase M: memory head (blocks 0..127, one b each) ----------------
    if (blk < 128) {
      const int b = blk;
      if (t == ilen) { loadWhead(W_ra); __syncthreads(); }
      float* logits = (float*)sm.un;
      float* pbuf   = (float*)(sm.un + 512);
      float* vred   = (float*)(sm.un + 1024);
      float* vsec   = (float*)(sm.un + 1536);
      const int n = wav * 32 + (lane & 31);
      const int kh = lane >> 5;
      const char* wrow = (const char*)sm.whead + (n << 10);
      const f16* hsrc = XPRH + (((size_t)nxt * 8 + (b >> 4)) * 72) * 128 + (b & 15) * 8;
      float av = 0.f;
      #pragma unroll 8
      for (int i = 0; i < 32; ++i) {
        half8 wv = *(const half8*)(wrow + (((kh * 32 + i + n) & 63) << 4));
        half8 hv = *(const half8*)(hsrc + (8 + kh * 32 + i) * 128);
        av = marnn_dot8(wv, hv, av);
      }
      av += __shfl_xor(av, 32, 64);
      if (lane < 32) logits[n] = av + (iswrite ? b_wa[n] : b_ra[n]);
      if (iswrite && wav == 1 && lane < 16)
        *(f32x4*)(vsec + lane * 4) = *(const f32x4*)(Vbuf + ((size_t)t * 128 + b) * 64 + lane * 4);
      __syncthreads();
      if (wav == 0) {
        float l0 = logits[lane], l1 = logits[lane + 64];
        float mx = fmaxf(l0, l1);
        #pragma unroll
        for (int off = 32; off > 0; off >>= 1) mx = fmaxf(mx, __shfl_xor(mx, off, 64));
        float e0 = __expf(l0 - mx), e1 = __expf(l1 - mx);
        float s = e0 + e1;
        #pragma unroll
        for (int off = 32; off > 0; off >>= 1) s += __shfl_xor(s, off, 64);
        float inv = 1.f / s;
        pbuf[lane] = e0 * inv; pbuf[lane + 64] = e1 * inv;
      }
      __syncthreads();
      if (iswrite) {
        float p = pbuf[tid >> 1];
        float* mrow = MEMB + (((size_t)b) * 128 + (tid >> 1)) * 64 + (tid & 1) * 32;
        const float* vv = vsec + (tid & 1) * 32;
        #pragma unroll
        for (int i2 = 0; i2 < 32; i2 += 4) {
          f32x4 mm = *(f32x4*)(mrow + i2);
          f32x4 v4 = *(const f32x4*)(vv + i2);
          mm = mm + p * v4;
          *(f32x4*)(mrow + i2) = mm;
        }
        if (tid < 64) out[(size_t)t * 73728 + b * 576 + 512 + tid] = r0v;
      } else {
        if (wav < 2) {
          const float* mcol = MEMB + (((size_t)b) * 128 + wav * 64) * 64 + lane;
          float a2 = 0.f;
          #pragma unroll 8
          for (int n2 = 0; n2 < 64; ++n2) a2 = fmaf(pbuf[wav * 64 + n2], mcol[n2 * 64], a2);
          vred[wav * 64 + lane] = a2;
        }
        __syncthreads();
        if (tid < 64) {
          float rv = vred[tid] + vred[64 + tid];
          out[(size_t)t * 73728 + b * 576 + 512 + tid] = rv;
          XPRH[(((size_t)nxt * 8 + (b >> 4)) * 72 + (tid >> 3)) * 128 + (b & 15) * 8 + (tid & 7)] = (f16)rv;
        }
      }
    }

    // ---- stage stores for step t+1 ----
    if (dostage) {
      u32x4* d0 = (u32x4*)sm.xl;
      d0[tid * 2] = sa0; d0[tid * 2 + 1] = sa1;
      u32x4* d1 = (u32x4*)(sm.xl + 10240);
      d1[tid * 4 + 0] = sb0; d1[tid * 4 + 1] = sb1;
      d1[tid * 4 + 2] = sb2; d1[tid * 4 + 3] = sb3;
    }

    // read phase: A_{t+1} consumes r_{t+1} from M_t -> need second barrier.
    // write phase: r unchanged; M_t/mem are block-private -> intra-block sync suffices.
    if (!iswrite && t + 1 < TSTEPS) marnn_fbar(FLAGS, blk, ++ep);
    else __syncthreads();
  }
}

// ---------------- host ----------------

extern "C" void kernel_launch(void* const* d_in, const int* in_sizes, int n_in,
                              void* d_out, int out_size, void* d_ws, size_t ws_size,
                              hipStream_t stream) {
  const float* embs = (const float*)d_in[0];
  const int*   ilen = (const int*)d_in[1];
  const float* w_ih = (const float*)d_in[2];
  const float* w_hh = (const float*)d_in[3];
  const float* b_ih = (const float*)d_in[4];
  const float* b_hh = (const float*)d_in[5];
  const float* h0   = (const float*)d_in[6];
  const float* c0   = (const float*)d_in[7];
  const float* r0   = (const float*)d_in[8];
  const float* W_wa = (const float*)d_in[9];
  const float* b_wa = (const float*)d_in[10];
  const float* W_wv = (const float*)d_in[11];
  const float* b_wv = (const float*)d_in[12];
  const float* W_ra = (const float*)d_in[13];
  const float* b_ra = (const float*)d_in[14];
  float* out = (float*)d_out;
  char* ws = (char*)d_ws;
  if (ws_size < WS_NEED) return;  // insufficient scratch: fail cleanly

  hipMemsetAsync(ws + OFF_MEM, 0, 4194304, stream);
  hipMemsetAsync(ws + OFF_BAR, 0, 1024, stream);
  marnn_packw<<<6656, 256, 0, stream>>>(w_ih, w_hh, b_ih, b_hh,
                                        (f16*)(ws + OFF_WP), (float*)(ws + OFF_BIAS));
  marnn_packemb<<<131072, 256, 0, stream>>>(embs, (f16*)(ws + OFF_EMBP));
  marnn_vpre<<<32768, 256, 0, stream>>>(embs, W_wv, b_wv, (float*)(ws + OFF_V));
  marnn_init<<<576, 256, 0, stream>>>(h0, r0, (f16*)(ws + OFF_XPRH));
  marnn_main<<<256, 256, 0, stream>>>(ilen, c0, r0, W_wa, b_wa, W_ra, b_ra, out, ws);
}

// Round 3
// 11896.038 us; speedup vs baseline: 4.0036x; 2.9609x over previous
//
#include <hip/hip_runtime.h>

typedef _Float16 f16;
typedef __attribute__((ext_vector_type(8))) _Float16 half8;
typedef __attribute__((ext_vector_type(2))) _Float16 half2v;
typedef __attribute__((ext_vector_type(4))) float f32x4;
typedef __attribute__((ext_vector_type(4))) unsigned int u32x4;

#define TSTEPS 1024

// ---- workspace layout (bytes) ----
static const size_t OFF_WP   = 0;           // f16 [128 ntile][26 ks][64 lane][8]     = 3,407,872
static const size_t OFF_BIAS = 3407872;     // f32 [2048] gate-interleaved            = 8,192
static const size_t OFF_EMBP = 3416064;     // f16 [1024 t][8 bg][32 kc][16 bl][8]    = 67,108,864
static const size_t OFF_V    = 70524928;    // f32 [1024 t][128 b][64 m]              = 33,554,432
static const size_t OFF_XPRH = 104079360;   // f16 [2 par][8 bg][72 kc][16 bl][8]     = 294,912
static const size_t OFF_MEM  = 104374272;   // f32 [128 b][128 n][64 m]               = 4,194,304
static const size_t OFF_BAR  = 108568576;   // u32 flags[8 groups][32] (128B/group)
static const size_t WS_NEED  = 108569600;

// ---------------- prologue kernels ----------------

__global__ void marnn_packw(const float* __restrict__ w_ih, const float* __restrict__ w_hh,
                            const float* __restrict__ b_ih, const float* __restrict__ b_hh,
                            f16* __restrict__ WP, float* __restrict__ biasP) {
  int idx = blockIdx.x * 256 + threadIdx.x;
  if (idx < 2048) {
    int j = idx >> 2, g = idx & 3, rg = g * 512 + j;
    biasP[idx] = b_ih[rg] + b_hh[rg];
  }
  if (idx >= 1703936) return;
  int e = idx & 7, l = (idx >> 3) & 63;
  int q = idx >> 9;
  int ks = q % 26; int ntile = q / 26;
  int n = ntile * 16 + (l & 15);
  int k = ks * 32 + (l >> 4) * 8 + e;
  int j2 = n >> 2, g2 = n & 3, rg2 = g2 * 512 + j2;
  float v = (k < 320) ? w_ih[(size_t)rg2 * 320 + k] : w_hh[(size_t)rg2 * 512 + (k - 320)];
  WP[idx] = (f16)v;
}

__global__ void marnn_packemb(const float* __restrict__ embs, f16* __restrict__ embsP) {
  long idx = (long)blockIdx.x * 256 + threadIdx.x;
  if (idx >= (long)1024 * 128 * 256) return;
  int e = idx & 7, bl = (idx >> 3) & 15, kc = (idx >> 7) & 31, bg = (idx >> 12) & 7;
  long t = idx >> 15;
  embsP[idx] = (f16)embs[((t * 128) + bg * 16 + bl) * 256 + kc * 8 + e];
}

__global__ void marnn_vpre(const float* __restrict__ embs, const float* __restrict__ W_wv,
                           const float* __restrict__ b_wv, float* __restrict__ V) {
  long idx = (long)blockIdx.x * 256 + threadIdx.x;
  if (idx >= (long)1024 * 128 * 64) return;
  int m = idx & 63; int b = (idx >> 6) & 127; long t = idx >> 13;
  const float* e = embs + (t * 128 + b) * 256;
  const float* w = W_wv + m * 256;
  float acc = b_wv[m];
  #pragma unroll 4
  for (int k = 0; k < 256; k += 4) {
    f32x4 e4 = *(const f32x4*)(e + k);
    f32x4 w4 = *(const f32x4*)(w + k);
    acc += e4[0]*w4[0] + e4[1]*w4[1] + e4[2]*w4[2] + e4[3]*w4[3];
  }
  V[idx] = acc;
}

__global__ void marnn_init(const float* __restrict__ h0, const float* __restrict__ r0,
                           f16* __restrict__ XPRH) {
  int idx = blockIdx.x * 256 + threadIdx.x;
  if (idx >= 147456) return;
  int e = idx & 7; int q = idx >> 7; int kcidx = q % 72;
  float v = (kcidx < 8) ? r0[kcidx * 8 + e] : h0[(kcidx - 8) * 8 + e];
  XPRH[idx] = (f16)v;
}

// ---------------- main persistent kernel ----------------

struct __align__(16) MarnnSMem {
  f16  whead[128 * 512];   // 131072 B, rotate-swizzled rows
  char xl[26624];          // X frags [104 kc][16 bl][8] f16; first 8KB doubles as gatebuf
  char un[4096];           // M-phase scratch: logits/pbuf/vred/vsec
};

__device__ __forceinline__ float marnn_dot8(half8 a, half8 b, float acc) {
#if __has_builtin(__builtin_amdgcn_fdot2)
  half2v a0 = {a[0],a[1]}, a1 = {a[2],a[3]}, a2 = {a[4],a[5]}, a3 = {a[6],a[7]};
  half2v b0 = {b[0],b[1]}, b1 = {b[2],b[3]}, b2 = {b[4],b[5]}, b3 = {b[6],b[7]};
  acc = __builtin_amdgcn_fdot2(a0, b0, acc, false);
  acc = __builtin_amdgcn_fdot2(a1, b1, acc, false);
  acc = __builtin_amdgcn_fdot2(a2, b2, acc, false);
  acc = __builtin_amdgcn_fdot2(a3, b3, acc, false);
#else
  #pragma unroll
  for (int e = 0; e < 8; ++e) acc += (float)a[e] * (float)b[e];
#endif
  return acc;
}

// 16-block group barrier: per-block flag on one 64B line; wave0 lanes 0-15 poll one line.
__device__ __forceinline__ void marnn_gbar(unsigned* gf, int ns, unsigned ep) {
  __syncthreads();
  if (threadIdx.x == 0) {
    __builtin_amdgcn_fence(__ATOMIC_RELEASE, "agent");
    __hip_atomic_store(gf + ns, ep, __ATOMIC_RELAXED, __HIP_MEMORY_SCOPE_AGENT);
  }
  if (threadIdx.x < 64) {
    for (;;) {
      unsigned v = (threadIdx.x < 16)
        ? __hip_atomic_load(gf + threadIdx.x, __ATOMIC_RELAXED, __HIP_MEMORY_SCOPE_AGENT)
        : ep;
      if (__all((int)(v >= ep))) break;
      __builtin_amdgcn_s_sleep(1);
    }
    __builtin_amdgcn_fence(__ATOMIC_ACQUIRE, "agent");
  }
  __syncthreads();
}

__global__ __launch_bounds__(512, 1)
void marnn_main(const int* __restrict__ ilen_p, const float* __restrict__ c0,
                const float* __restrict__ r0,
                const float* __restrict__ W_wa, const float* __restrict__ b_wa,
                const float* __restrict__ W_ra, const float* __restrict__ b_ra,
                float* __restrict__ out, char* __restrict__ ws) {
  __shared__ MarnnSMem sm;

  const f16*   WP    = (const f16*)(ws + OFF_WP);
  const float* biasP = (const float*)(ws + OFF_BIAS);
  const f16*   embsP = (const f16*)(ws + OFF_EMBP);
  const float* Vbuf  = (const float*)(ws + OFF_V);
  f16*         XPRH  = (f16*)(ws + OFF_XPRH);
  float*       MEMB  = (float*)(ws + OFF_MEM);
  unsigned*    FLAGS = (unsigned*)(ws + OFF_BAR);

  const int blk = blockIdx.x, tid = threadIdx.x;
  const int wav = tid >> 6, lane = tid & 63;
  const int g = blk >> 4, ns = blk & 15;   // group (batch-group of 16) x n-slice (128 rows)
  const int ilen = ilen_p[0];
  unsigned* gf = FLAGS + g * 32;

  // persistent B-fragments: wave owns n-tile (ns*8 + wav), 16 rows
  half8 bfr[26];
  {
    const f16* wpb = WP + ((size_t)(ns * 8 + wav) * 26) * 512 + lane * 8;
    #pragma unroll
    for (int ks = 0; ks < 26; ++ks) bfr[ks] = *(const half8*)(wpb + ks * 512);
  }

  auto loadWhead = [&](const float* Wsrc) {
    for (int i = tid; i < 8192; i += 512) {
      int n = i >> 6, slot = i & 63;
      const float* s = Wsrc + n * 512 + slot * 8;
      f32x4 a = *(const f32x4*)(s), b2 = *(const f32x4*)(s + 4);
      half8 hv;
      hv[0]=(f16)a[0]; hv[1]=(f16)a[1]; hv[2]=(f16)a[2]; hv[3]=(f16)a[3];
      hv[4]=(f16)b2[0]; hv[5]=(f16)b2[1]; hv[6]=(f16)b2[2]; hv[7]=(f16)b2[3];
      *(half8*)((char*)sm.whead + (n << 10) + (((slot + n) & 63) << 4)) = hv;
    }
  };
  loadWhead(ilen > 0 ? W_wa : W_ra);

  // initial X stage (t=0, parity 0): emb 8KB + h 16KB
  {
    const u32x4* s0 = (const u32x4*)(embsP + ((size_t)0 * 8 + g) * 4096);
    ((u32x4*)sm.xl)[tid] = s0[tid];
    const u32x4* s1 = (const u32x4*)(XPRH + (((size_t)0 * 8 + g) * 72 + 8) * 128);
    u32x4* d1 = (u32x4*)(sm.xl + 10240);
    d1[tid * 2] = s1[tid * 2]; d1[tid * 2 + 1] = s1[tid * 2 + 1];
  }
  __syncthreads();

  // activation ownership: thread -> (b_l = tid>>5, jj = tid&31); c in register
  const int b_l = tid >> 5, jj = tid & 31;
  const int jg = ns * 32 + jj;               // j in [0,512)
  float c = c0[jg];
  const f32x4 bias4 = *(const f32x4*)(biasP + ns * 128 + jj * 4);
  const float r0v = (tid < 64) ? r0[tid] : 0.f;
  const int b = g * 16 + ns;                 // this block's memory-head batch

  // M-phase per-thread constants (GEMV on waves 0-3)
  const int mn = (wav & 3) * 32 + (lane & 31);
  const int kh = lane >> 5;
  const float bwa_v = b_wa[mn], bra_v = b_ra[mn];

  half8 rf0{}, rf1{};
  unsigned ep = 0;

  for (int t = 0; t < TSTEPS; ++t) {
    const int par = t & 1, nxt = par ^ 1;
    const bool iswrite = (t < ilen);

    // r fragments: constant (=r0) through the whole write phase; reload per read step
    if (t == 0 || t > ilen) {
      const f16* rbase = XPRH + (((size_t)par * 8 + g) * 72) * 128 + (lane >> 4) * 128 + (lane & 15) * 8;
      rf0 = *(const half8*)(rbase);
      rf1 = *(const half8*)(rbase + 512);
    }

    // ---------------- phase A: gates GEMM + activations ----------------
    f32x4 acc = {0.f, 0.f, 0.f, 0.f};
    const char* xb = sm.xl + (lane >> 4) * 256 + (lane & 15) * 16;
    #pragma unroll
    for (int ks = 0; ks < 26; ++ks) {
      half8 af = (ks == 8) ? rf0 : (ks == 9) ? rf1 : *(const half8*)(xb + ks * 1024);
      acc = __builtin_amdgcn_mfma_f32_16x16x32_f16(af, bfr[ks], acc, 0, 0, 0);
    }
    __syncthreads();                         // all waves done reading xl
    {
      float* gatebuf = (float*)sm.xl;        // [16 b][128 n-local] f32 (aliases xl)
      #pragma unroll
      for (int r = 0; r < 4; ++r)
        gatebuf[((lane >> 4) * 4 + r) * 128 + wav * 16 + (lane & 15)] = acc[r];
    }
    __syncthreads();
    {
      const float* gatebuf = (const float*)sm.xl;
      f32x4 g4 = *(const f32x4*)(gatebuf + b_l * 128 + jj * 4);
      float gi = g4[0] + bias4[0], gf_ = g4[1] + bias4[1];
      float gg = g4[2] + bias4[2], go = g4[3] + bias4[3];
      float si = 1.f / (1.f + __expf(-gi));
      float sf = 1.f / (1.f + __expf(-gf_));
      float so = 1.f / (1.f + __expf(-go));
      c = sf * c + si * tanhf(gg);
      float h = so * tanhf(c);
      __builtin_nontemporal_store(h, &out[(size_t)t * 73728 + (g * 16 + b_l) * 576 + jg]);
      XPRH[(((size_t)nxt * 8 + g) * 72 + 8 + (jg >> 3)) * 128 + b_l * 8 + (jj & 7)] = (f16)h;
    }
    marnn_gbar(gf, ns, ++ep);                // h_{t+1} visible group-wide

    // ---- stage loads for t+1 (emb + fresh h); stores deferred past M ----
    const bool dostage = (t + 1 < TSTEPS);
    u32x4 sa{}, sb0{}, sb1{};
    if (dostage) {
      sa = ((const u32x4*)(embsP + (((size_t)(t + 1) * 8) + g) * 4096))[tid];
      const u32x4* s1 = (const u32x4*)(XPRH + (((size_t)nxt * 8 + g) * 72 + 8) * 128);
      sb0 = s1[tid * 2]; sb1 = s1[tid * 2 + 1];
    }

    // ---------------- phase M: memory head (every block: batch b) ----------------
    {
      if (t == ilen) { loadWhead(W_ra); __syncthreads(); }
      float* logits = (float*)sm.un;           // 512 B
      float* pbuf   = (float*)(sm.un + 512);   // 512 B
      float* vred   = (float*)(sm.un + 1024);  // 2 KB
      float* vsec   = (float*)(sm.un + 3072);  // 256 B
      const f16* hsrc = XPRH + (((size_t)nxt * 8 + g) * 72) * 128 + ns * 8;
      if (wav < 4) {
        const char* wrow = (const char*)sm.whead + (mn << 10);
        float av = 0.f;
        #pragma unroll 8
        for (int i = 0; i < 32; ++i) {
          half8 wv = *(const half8*)(wrow + (((kh * 32 + i + mn) & 63) << 4));
          half8 hv = *(const half8*)(hsrc + (8 + kh * 32 + i) * 128);
          av = marnn_dot8(wv, hv, av);
        }
        av += __shfl_xor(av, 32, 64);
        if (lane < 32) logits[mn] = av + (iswrite ? bwa_v : bra_v);
      } else if (iswrite && wav == 4 && lane < 16) {
        *(f32x4*)(vsec + lane * 4) = *(const f32x4*)(Vbuf + ((size_t)t * 128 + b) * 64 + lane * 4);
      }
      __syncthreads();
      if (wav == 0) {
        float l0 = logits[lane], l1 = logits[lane + 64];
        float mx = fmaxf(l0, l1);
        #pragma unroll
        for (int off = 32; off > 0; off >>= 1) mx = fmaxf(mx, __shfl_xor(mx, off, 64));
        float e0 = __expf(l0 - mx), e1 = __expf(l1 - mx);
        float s = e0 + e1;
        #pragma unroll
        for (int off = 32; off > 0; off >>= 1) s += __shfl_xor(s, off, 64);
        float inv = 1.f / s;
        pbuf[lane] = e0 * inv; pbuf[lane + 64] = e1 * inv;
      }
      __syncthreads();
      if (iswrite) {
        // mem[b] += wa ⊗ v : thread -> (n = tid>>2, m-quarter = tid&3)
        float p = pbuf[tid >> 2];
        float* mrow = MEMB + (((size_t)b) * 128 + (tid >> 2)) * 64 + (tid & 3) * 16;
        const float* vv = vsec + (tid & 3) * 16;
        #pragma unroll
        for (int i2 = 0; i2 < 16; i2 += 4) {
          f32x4 mm = *(f32x4*)(mrow + i2);
          f32x4 v4 = *(const f32x4*)(vv + i2);
          mm = mm + p * v4;
          *(f32x4*)(mrow + i2) = mm;
        }
        if (tid < 64)
          __builtin_nontemporal_store(r0v, &out[(size_t)t * 73728 + b * 576 + 512 + tid]);
      } else {
        // r = ra · mem[b] : thread -> (m = tid&63, n-chunk = wav of 16)
        const int m = tid & 63;
        const float* mcol = MEMB + (((size_t)b) * 128 + wav * 16) * 64 + m;
        float a2 = 0.f;
        #pragma unroll
        for (int n2 = 0; n2 < 16; ++n2) a2 = fmaf(pbuf[wav * 16 + n2], mcol[n2 * 64], a2);
        vred[wav * 64 + m] = a2;
        __syncthreads();
        if (tid < 64) {
          float rv = 0.f;
          #pragma unroll
          for (int nc = 0; nc < 8; ++nc) rv += vred[nc * 64 + tid];
          __builtin_nontemporal_store(rv, &out[(size_t)t * 73728 + b * 576 + 512 + tid]);
          XPRH[(((size_t)nxt * 8 + g) * 72 + (tid >> 3)) * 128 + ns * 8 + (tid & 7)] = (f16)rv;
        }
      }
    }

    // ---- stage stores for t+1 into xl ----
    if (dostage) {
      ((u32x4*)sm.xl)[tid] = sa;
      u32x4* d1 = (u32x4*)(sm.xl + 10240);
      d1[tid * 2] = sb0; d1[tid * 2 + 1] = sb1;
    }

    // read phase: A_{t+1} consumes r_{t+1} from other blocks -> group barrier.
    // write phase: r static, mem block-private -> intra-block sync suffices.
    if (!iswrite && t + 1 < TSTEPS) marnn_gbar(gf, ns, ++ep);
    else __syncthreads();
  }
}

// ---------------- host ----------------

extern "C" void kernel_launch(void* const* d_in, const int* in_sizes, int n_in,
                              void* d_out, int out_size, void* d_ws, size_t ws_size,
                              hipStream_t stream) {
  const float* embs = (const float*)d_in[0];
  const int*   ilen = (const int*)d_in[1];
  const float* w_ih = (const float*)d_in[2];
  const float* w_hh = (const float*)d_in[3];
  const float* b_ih = (const float*)d_in[4];
  const float* b_hh = (const float*)d_in[5];
  const float* h0   = (const float*)d_in[6];
  const float* c0   = (const float*)d_in[7];
  const float* r0   = (const float*)d_in[8];
  const float* W_wa = (const float*)d_in[9];
  const float* b_wa = (const float*)d_in[10];
  const float* W_wv = (const float*)d_in[11];
  const float* b_wv = (const float*)d_in[12];
  const float* W_ra = (const float*)d_in[13];
  const float* b_ra = (const float*)d_in[14];
  float* out = (float*)d_out;
  char* ws = (char*)d_ws;
  if (ws_size < WS_NEED) return;  // insufficient scratch: fail cleanly

  hipMemsetAsync(ws + OFF_MEM, 0, 4194304, stream);
  hipMemsetAsync(ws + OFF_BAR, 0, 1024, stream);
  marnn_packw<<<6656, 256, 0, stream>>>(w_ih, w_hh, b_ih, b_hh,
                                        (f16*)(ws + OFF_WP), (float*)(ws + OFF_BIAS));
  marnn_packemb<<<131072, 256, 0, stream>>>(embs, (f16*)(ws + OFF_EMBP));
  marnn_vpre<<<32768, 256, 0, stream>>>(embs, W_wv, b_wv, (float*)(ws + OFF_V));
  marnn_init<<<576, 256, 0, stream>>>(h0, r0, (f16*)(ws + OFF_XPRH));
  marnn_main<<<128, 512, 0, stream>>>(ilen, c0, r0, W_wa, b_wa, W_ra, b_ra, out, ws);
}

// Round 4
// 8289.969 us; speedup vs baseline: 5.7452x; 1.4350x over previous
//
#include <hip/hip_runtime.h>

typedef _Float16 f16;
typedef __attribute__((ext_vector_type(8))) _Float16 half8;
typedef __attribute__((ext_vector_type(2))) _Float16 half2v;
typedef __attribute__((ext_vector_type(4))) float f32x4;
typedef __attribute__((ext_vector_type(4))) unsigned int u32x4;
typedef unsigned long long u64;

#define TSTEPS 1024

// ---- workspace layout (bytes) ----
static const size_t OFF_WP   = 0;           // f16 [128 ntile][26 ks][64 lane][8]     = 3,407,872
static const size_t OFF_BIAS = 3407872;     // f32 [2048] gate-interleaved            = 8,192
static const size_t OFF_EMBP = 3416064;     // f16 [1024 t][8 bg][32 kc][16 bl][8]    = 67,108,864
static const size_t OFF_V    = 70524928;    // f32 [1024 t][128 b][64 m]              = 33,554,432
static const size_t OFF_XPRH = 104079360;   // f16 [2 par][8 bg][72 kc][16 bl][8]     = 294,912
static const size_t OFF_MEM  = 104374272;   // f32 [128 b][128 n][64 m]               = 4,194,304
static const size_t OFF_BAR  = 108568576;   // u32 flags[8 groups][32]: [0..15]=h, [16..31]=r
static const size_t WS_NEED  = 108569600;

// ---------------- prologue kernels ----------------

__global__ void marnn_packw(const float* __restrict__ w_ih, const float* __restrict__ w_hh,
                            const float* __restrict__ b_ih, const float* __restrict__ b_hh,
                            f16* __restrict__ WP, float* __restrict__ biasP) {
  int idx = blockIdx.x * 256 + threadIdx.x;
  if (idx < 2048) {
    int j = idx >> 2, g = idx & 3, rg = g * 512 + j;
    biasP[idx] = b_ih[rg] + b_hh[rg];
  }
  if (idx >= 1703936) return;
  int e = idx & 7, l = (idx >> 3) & 63;
  int q = idx >> 9;
  int ks = q % 26; int ntile = q / 26;
  int n = ntile * 16 + (l & 15);
  int k = ks * 32 + (l >> 4) * 8 + e;
  int j2 = n >> 2, g2 = n & 3, rg2 = g2 * 512 + j2;
  float v = (k < 320) ? w_ih[(size_t)rg2 * 320 + k] : w_hh[(size_t)rg2 * 512 + (k - 320)];
  WP[idx] = (f16)v;
}

__global__ void marnn_packemb(const float* __restrict__ embs, f16* __restrict__ embsP) {
  long idx = (long)blockIdx.x * 256 + threadIdx.x;
  if (idx >= (long)1024 * 128 * 256) return;
  int e = idx & 7, bl = (idx >> 3) & 15, kc = (idx >> 7) & 31, bg = (idx >> 12) & 7;
  long t = idx >> 15;
  embsP[idx] = (f16)embs[((t * 128) + bg * 16 + bl) * 256 + kc * 8 + e];
}

__global__ void marnn_vpre(const float* __restrict__ embs, const float* __restrict__ W_wv,
                           const float* __restrict__ b_wv, float* __restrict__ V) {
  long idx = (long)blockIdx.x * 256 + threadIdx.x;
  if (idx >= (long)1024 * 128 * 64) return;
  int m = idx & 63; int b = (idx >> 6) & 127; long t = idx >> 13;
  const float* e = embs + (t * 128 + b) * 256;
  const float* w = W_wv + m * 256;
  float acc = b_wv[m];
  #pragma unroll 4
  for (int k = 0; k < 256; k += 4) {
    f32x4 e4 = *(const f32x4*)(e + k);
    f32x4 w4 = *(const f32x4*)(w + k);
    acc += e4[0]*w4[0] + e4[1]*w4[1] + e4[2]*w4[2] + e4[3]*w4[3];
  }
  V[idx] = acc;
}

__global__ void marnn_init(const float* __restrict__ h0, const float* __restrict__ r0,
                           f16* __restrict__ XPRH) {
  int idx = blockIdx.x * 256 + threadIdx.x;
  if (idx >= 147456) return;
  int e = idx & 7; int q = idx >> 7; int kcidx = q % 72;
  float v = (kcidx < 8) ? r0[kcidx * 8 + e] : h0[(kcidx - 8) * 8 + e];
  XPRH[idx] = (f16)v;
}

// ---------------- main persistent kernel ----------------

struct __align__(16) MarnnSMem {
  f16  whead[128 * 512];   // 131072 B, rotate-swizzled rows
  char xl[26624];          // X frags [104 kc][16 bl][8] f16; first 8KB doubles as gatebuf
  char un[4096];           // M-phase scratch: logits/pbuf/vred/vsec
};

__device__ __forceinline__ float marnn_dot8(half8 a, half8 b, float acc) {
#if __has_builtin(__builtin_amdgcn_fdot2)
  half2v a0 = {a[0],a[1]}, a1 = {a[2],a[3]}, a2 = {a[4],a[5]}, a3 = {a[6],a[7]};
  half2v b0 = {b[0],b[1]}, b1 = {b[2],b[3]}, b2 = {b[4],b[5]}, b3 = {b[6],b[7]};
  acc = __builtin_amdgcn_fdot2(a0, b0, acc, false);
  acc = __builtin_amdgcn_fdot2(a1, b1, acc, false);
  acc = __builtin_amdgcn_fdot2(a2, b2, acc, false);
  acc = __builtin_amdgcn_fdot2(a3, b3, acc, false);
#else
  #pragma unroll
  for (int e = 0; e < 8; ++e) acc += (float)a[e] * (float)b[e];
#endif
  return acc;
}

// LLC-coherent primitives: agent-scope relaxed atomics (sc0+sc1, no cache fences)
__device__ __forceinline__ unsigned ld_flag(const unsigned* p) {
  return __hip_atomic_load(p, __ATOMIC_RELAXED, __HIP_MEMORY_SCOPE_AGENT);
}
__device__ __forceinline__ void st_flag(unsigned* p, unsigned v) {
  __hip_atomic_store(p, v, __ATOMIC_RELAXED, __HIP_MEMORY_SCOPE_AGENT);
}
__device__ __forceinline__ u64 ld_llc64(const void* p) {
  return __hip_atomic_load((const u64*)p, __ATOMIC_RELAXED, __HIP_MEMORY_SCOPE_AGENT);
}
__device__ __forceinline__ void st_llc32(void* p, unsigned v) {
  __hip_atomic_store((unsigned*)p, v, __ATOMIC_RELAXED, __HIP_MEMORY_SCOPE_AGENT);
}

// wave-level poll: lanes 0-15 watch one 64B flag line until all >= ep
__device__ __forceinline__ void poll16(const unsigned* line, unsigned ep) {
  int l = threadIdx.x & 63;
  for (;;) {
    unsigned v = (l < 16) ? ld_flag(line + l) : ep;
    if (__all((int)(v >= ep))) break;
    __builtin_amdgcn_s_sleep(1);
  }
  asm volatile("" ::: "memory");
}

union H2U { f16 f; unsigned short u; };

__global__ __launch_bounds__(512, 1)
void marnn_main(const int* __restrict__ ilen_p, const float* __restrict__ c0,
                const float* __restrict__ r0,
                const float* __restrict__ W_wa, const float* __restrict__ b_wa,
                const float* __restrict__ W_ra, const float* __restrict__ b_ra,
                float* __restrict__ out, char* __restrict__ ws) {
  __shared__ MarnnSMem sm;

  const f16*   WP    = (const f16*)(ws + OFF_WP);
  const float* biasP = (const float*)(ws + OFF_BIAS);
  const f16*   embsP = (const f16*)(ws + OFF_EMBP);
  const float* Vbuf  = (const float*)(ws + OFF_V);
  f16*         XPRH  = (f16*)(ws + OFF_XPRH);
  float*       MEMB  = (float*)(ws + OFF_MEM);
  unsigned*    FLAGS = (unsigned*)(ws + OFF_BAR);

  const int blk = blockIdx.x, tid = threadIdx.x;
  const int wav = tid >> 6, lane = tid & 63;
  const int g = blk >> 4, ns = blk & 15;   // group (batch-group of 16) x n-slice (128 rows)
  const int ilen = ilen_p[0];
  unsigned* gfh = FLAGS + g * 32;          // h flags, one 64B line
  unsigned* gfr = gfh + 16;                // r flags, next 64B line

  // persistent B-fragments: wave owns n-tile (ns*8 + wav), 16 rows
  half8 bfr[26];
  {
    const f16* wpb = WP + ((size_t)(ns * 8 + wav) * 26) * 512 + lane * 8;
    #pragma unroll
    for (int ks = 0; ks < 26; ++ks) bfr[ks] = *(const half8*)(wpb + ks * 512);
  }

  auto loadWhead = [&](const float* Wsrc) {
    for (int i = tid; i < 8192; i += 512) {
      int n = i >> 6, slot = i & 63;
      const float* s = Wsrc + n * 512 + slot * 8;
      f32x4 a = *(const f32x4*)(s), b2 = *(const f32x4*)(s + 4);
      half8 hv;
      hv[0]=(f16)a[0]; hv[1]=(f16)a[1]; hv[2]=(f16)a[2]; hv[3]=(f16)a[3];
      hv[4]=(f16)b2[0]; hv[5]=(f16)b2[1]; hv[6]=(f16)b2[2]; hv[7]=(f16)b2[3];
      *(half8*)((char*)sm.whead + (n << 10) + (((slot + n) & 63) << 4)) = hv;
    }
  };
  loadWhead(ilen > 0 ? W_wa : W_ra);

  // initial X stage (t=0, parity 0): emb 8KB + h 16KB (plain: kernel-boundary visibility)
  {
    const u32x4* s0 = (const u32x4*)(embsP + ((size_t)0 * 8 + g) * 4096);
    ((u32x4*)sm.xl)[tid] = s0[tid];
    const u32x4* s1 = (const u32x4*)(XPRH + (((size_t)0 * 8 + g) * 72 + 8) * 128);
    u32x4* d1 = (u32x4*)(sm.xl + 10240);
    d1[tid * 2] = s1[tid * 2]; d1[tid * 2 + 1] = s1[tid * 2 + 1];
  }
  __syncthreads();

  // activation ownership: thread -> (b_l = tid>>5, jj = tid&31); c in register
  const int b_l = tid >> 5, jj = tid & 31;
  const int jg = ns * 32 + jj;               // j in [0,512)
  float c = c0[jg];
  const f32x4 bias4 = *(const f32x4*)(biasP + ns * 128 + jj * 4);
  const float r0v = (tid < 64) ? r0[tid] : 0.f;
  const int b = g * 16 + ns;                 // this block's memory-head batch

  // M-phase per-thread constants (GEMV on waves 0-3)
  const int mn = (wav & 3) * 32 + (lane & 31);
  const int kh = lane >> 5;
  const float bwa_v = b_wa[mn], bra_v = b_ra[mn];

  // r fragments: constant (=r0) through t <= ilen; then LLC-reloaded per read step
  half8 rf0, rf1;
  {
    const f16* rbase = XPRH + ((size_t)g * 72) * 128 + (lane >> 4) * 128 + (lane & 15) * 8;
    rf0 = *(const half8*)(rbase);
    rf1 = *(const half8*)(rbase + 512);
  }

  for (int t = 0; t < TSTEPS; ++t) {
    const int par = t & 1, nxt = par ^ 1;
    const bool iswrite = (t < ilen);

    // ---------------- phase A: gates GEMM + activations ----------------
    f32x4 acc = {0.f, 0.f, 0.f, 0.f};
    const char* xb = sm.xl + (lane >> 4) * 256 + (lane & 15) * 16;
    #pragma unroll
    for (int ks = 0; ks < 8; ++ks)       // emb part
      acc = __builtin_amdgcn_mfma_f32_16x16x32_f16(*(const half8*)(xb + ks * 1024), bfr[ks], acc, 0, 0, 0);
    #pragma unroll
    for (int ks = 10; ks < 26; ++ks)     // h part
      acc = __builtin_amdgcn_mfma_f32_16x16x32_f16(*(const half8*)(xb + ks * 1024), bfr[ks], acc, 0, 0, 0);
    if (t > ilen) {
      // r produced by previous read-step M; wave-level wait, LLC load
      poll16(gfr, (unsigned)(t - ilen));
      const u64* rp = (const u64*)(XPRH + (((size_t)par * 8 + g) * 72) * 128 + (lane >> 4) * 128 + (lane & 15) * 8);
      union { u64 u[2]; half8 h; } c0v, c1v;
      c0v.u[0] = ld_llc64(rp);       c0v.u[1] = ld_llc64(rp + 1);
      c1v.u[0] = ld_llc64(rp + 128); c1v.u[1] = ld_llc64(rp + 129);
      rf0 = c0v.h; rf1 = c1v.h;
    }
    acc = __builtin_amdgcn_mfma_f32_16x16x32_f16(rf0, bfr[8], acc, 0, 0, 0);
    acc = __builtin_amdgcn_mfma_f32_16x16x32_f16(rf1, bfr[9], acc, 0, 0, 0);
    __syncthreads();                         // all waves done reading xl
    {
      float* gatebuf = (float*)sm.xl;        // [16 b][128 n-local] f32 (aliases xl)
      #pragma unroll
      for (int r = 0; r < 4; ++r)
        gatebuf[((lane >> 4) * 4 + r) * 128 + wav * 16 + (lane & 15)] = acc[r];
    }
    __syncthreads();
    {
      const float* gatebuf = (const float*)sm.xl;
      f32x4 g4 = *(const f32x4*)(gatebuf + b_l * 128 + jj * 4);
      float gi = g4[0] + bias4[0], gf_ = g4[1] + bias4[1];
      float gg = g4[2] + bias4[2], go = g4[3] + bias4[3];
      float si = 1.f / (1.f + __expf(-gi));
      float sf = 1.f / (1.f + __expf(-gf_));
      float so = 1.f / (1.f + __expf(-go));
      c = sf * c + si * tanhf(gg);
      float h = so * tanhf(c);
      __builtin_nontemporal_store(h, &out[(size_t)t * 73728 + (g * 16 + b_l) * 576 + jg]);
      // h -> XPRH[nxt] via LLC write-through (pair 2 f16 into one u32 store)
      H2U cv; cv.f = (f16)h;
      int o = __shfl_down((int)cv.u, 1, 64);
      if (!(tid & 1))
        st_llc32(&XPRH[(((size_t)nxt * 8 + g) * 72 + 8 + (jg >> 3)) * 128 + b_l * 8 + (jj & 7)],
                 ((unsigned)cv.u) | (((unsigned)(unsigned short)o) << 16));
    }

    // ---------------- h exchange + X staging for t+1 ----------------
    asm volatile("s_waitcnt vmcnt(0)" ::: "memory");   // h stores globally visible
    __syncthreads();
    if (tid == 0) st_flag(gfh + ns, (unsigned)(t + 1));
    u32x4 sa = {0u, 0u, 0u, 0u};
    if (t + 1 < TSTEPS)                                // emb prefetch (independent of flag)
      sa = ((const u32x4*)(embsP + (((size_t)(t + 1) * 8) + g) * 4096))[tid];
    poll16(gfh, (unsigned)(t + 1));
    u64 hb0, hb1, hb2, hb3;
    {
      const u64* s1 = (const u64*)(XPRH + (((size_t)nxt * 8 + g) * 72 + 8) * 128);
      hb0 = ld_llc64(s1 + tid * 4 + 0); hb1 = ld_llc64(s1 + tid * 4 + 1);
      hb2 = ld_llc64(s1 + tid * 4 + 2); hb3 = ld_llc64(s1 + tid * 4 + 3);
    }
    ((u32x4*)sm.xl)[tid] = sa;
    {
      u64* d1 = (u64*)(sm.xl + 10240);
      d1[tid * 4 + 0] = hb0; d1[tid * 4 + 1] = hb1;
      d1[tid * 4 + 2] = hb2; d1[tid * 4 + 3] = hb3;
    }
    __syncthreads();                         // xl holds emb_{t+1} + h_{t+1}

    // ---------------- phase M: memory head (each block: batch b) ----------------
    {
      if (t == ilen) { loadWhead(W_ra); __syncthreads(); }
      float* logits = (float*)sm.un;           // 512 B
      float* pbuf   = (float*)(sm.un + 512);   // 512 B
      float* vred   = (float*)(sm.un + 1024);  // 2 KB
      float* vsec   = (float*)(sm.un + 3072);  // 256 B
      if (wav < 4) {
        const char* wrow = (const char*)sm.whead + (mn << 10);
        float av = 0.f;
        #pragma unroll 8
        for (int i = 0; i < 32; ++i) {
          half8 wv = *(const half8*)(wrow + (((kh * 32 + i + mn) & 63) << 4));
          half8 hv = *(const half8*)(sm.xl + 10240 + (kh * 32 + i) * 256 + ns * 16);  // h_{t+1}[b], LDS broadcast
          av = marnn_dot8(wv, hv, av);
        }
        av += __shfl_xor(av, 32, 64);
        if (lane < 32) logits[mn] = av + (iswrite ? bwa_v : bra_v);
      } else if (iswrite && wav == 4 && lane < 16) {
        *(f32x4*)(vsec + lane * 4) = *(const f32x4*)(Vbuf + ((size_t)t * 128 + b) * 64 + lane * 4);
      }
      __syncthreads();
      if (wav == 0) {
        float l0 = logits[lane], l1 = logits[lane + 64];
        float mx = fmaxf(l0, l1);
        #pragma unroll
        for (int off = 32; off > 0; off >>= 1) mx = fmaxf(mx, __shfl_xor(mx, off, 64));
        float e0 = __expf(l0 - mx), e1 = __expf(l1 - mx);
        float s = e0 + e1;
        #pragma unroll
        for (int off = 32; off > 0; off >>= 1) s += __shfl_xor(s, off, 64);
        float inv = 1.f / s;
        pbuf[lane] = e0 * inv; pbuf[lane + 64] = e1 * inv;
      }
      __syncthreads();
      if (iswrite) {
        // mem[b] += wa ⊗ v : thread -> (n = tid>>2, m-quarter = tid&3); plain L2-resident
        float p = pbuf[tid >> 2];
        float* mrow = MEMB + (((size_t)b) * 128 + (tid >> 2)) * 64 + (tid & 3) * 16;
        const float* vv = vsec + (tid & 3) * 16;
        #pragma unroll
        for (int i2 = 0; i2 < 16; i2 += 4) {
          f32x4 mm = *(f32x4*)(mrow + i2);
          f32x4 v4 = *(const f32x4*)(vv + i2);
          mm = mm + p * v4;
          *(f32x4*)(mrow + i2) = mm;
        }
        if (tid < 64)
          __builtin_nontemporal_store(r0v, &out[(size_t)t * 73728 + b * 576 + 512 + tid]);
      } else {
        // r = ra · mem[b] : thread -> (m = tid&63, n-chunk = wav of 16)
        const int m = tid & 63;
        const float* mcol = MEMB + (((size_t)b) * 128 + wav * 16) * 64 + m;
        float a2 = 0.f;
        #pragma unroll
        for (int n2 = 0; n2 < 16; ++n2) a2 = fmaf(pbuf[wav * 16 + n2], mcol[n2 * 64], a2);
        vred[wav * 64 + m] = a2;
        __syncthreads();
        if (tid < 64) {
          float rv = 0.f;
          #pragma unroll
          for (int nc = 0; nc < 8; ++nc) rv += vred[nc * 64 + tid];
          __builtin_nontemporal_store(rv, &out[(size_t)t * 73728 + b * 576 + 512 + tid]);
          H2U cr; cr.f = (f16)rv;
          int o2 = __shfl_down((int)cr.u, 1, 64);
          if (!(tid & 1))
            st_llc32(&XPRH[(((size_t)nxt * 8 + g) * 72 + (tid >> 3)) * 128 + ns * 8 + (tid & 7)],
                     ((unsigned)cr.u) | (((unsigned)(unsigned short)o2) << 16));
          asm volatile("s_waitcnt vmcnt(0)" ::: "memory");  // r stores visible (wave-local)
          if (tid == 0) st_flag(gfr + ns, (unsigned)(t - ilen + 1));
        }
        // no block barrier here: waves 1-7 run ahead into A_{t+1}; its r-poll
        // waits on gfr, and its first __syncthreads re-converges the block.
      }
    }
  }
}

// ---------------- host ----------------

extern "C" void kernel_launch(void* const* d_in, const int* in_sizes, int n_in,
                              void* d_out, int out_size, void* d_ws, size_t ws_size,
                              hipStream_t stream) {
  const float* embs = (const float*)d_in[0];
  const int*   ilen = (const int*)d_in[1];
  const float* w_ih = (const float*)d_in[2];
  const float* w_hh = (const float*)d_in[3];
  const float* b_ih = (const float*)d_in[4];
  const float* b_hh = (const float*)d_in[5];
  const float* h0   = (const float*)d_in[6];
  const float* c0   = (const float*)d_in[7];
  const float* r0   = (const float*)d_in[8];
  const float* W_wa = (const float*)d_in[9];
  const float* b_wa = (const float*)d_in[10];
  const float* W_wv = (const float*)d_in[11];
  const float* b_wv = (const float*)d_in[12];
  const float* W_ra = (const float*)d_in[13];
  const float* b_ra = (const float*)d_in[14];
  float* out = (float*)d_out;
  char* ws = (char*)d_ws;
  if (ws_size < WS_NEED) return;  // insufficient scratch: fail cleanly

  hipMemsetAsync(ws + OFF_MEM, 0, 4194304, stream);
  hipMemsetAsync(ws + OFF_BAR, 0, 1024, stream);
  marnn_packw<<<6656, 256, 0, stream>>>(w_ih, w_hh, b_ih, b_hh,
                                        (f16*)(ws + OFF_WP), (float*)(ws + OFF_BIAS));
  marnn_packemb<<<131072, 256, 0, stream>>>(embs, (f16*)(ws + OFF_EMBP));
  marnn_vpre<<<32768, 256, 0, stream>>>(embs, W_wv, b_wv, (float*)(ws + OFF_V));
  marnn_init<<<576, 256, 0, stream>>>(h0, r0, (f16*)(ws + OFF_XPRH));
  marnn_main<<<128, 512, 0, stream>>>(ilen, c0, r0, W_wa, b_wa, W_ra, b_ra, out, ws);
}

// Round 5
// 6647.507 us; speedup vs baseline: 7.1647x; 1.2471x over previous
//
#include <hip/hip_runtime.h>

typedef _Float16 f16;
typedef __attribute__((ext_vector_type(8))) _Float16 half8;
typedef __attribute__((ext_vector_type(2))) _Float16 half2v;
typedef __attribute__((ext_vector_type(4))) float f32x4;
typedef __attribute__((ext_vector_type(4))) unsigned int u32x4;
typedef unsigned long long u64;

#define TSTEPS 1024

// ---- workspace layout (bytes) ----
static const size_t OFF_WP   = 0;           // f16 [128 ntile][26 ks][64 lane][8]     = 3,407,872
static const size_t OFF_BIAS = 3407872;     // f32 [2048] gate-interleaved            = 8,192
static const size_t OFF_EMBP = 3416064;     // f16 [1024 t][8 bg][32 kc][16 bl][8]    = 67,108,864
static const size_t OFF_V    = 70524928;    // f32 [1024 t][128 b][64 m]              = 33,554,432
static const size_t OFF_XPRH = 104079360;   // f16 [2 par][8 bg][72 kc][16 bl][8]     = 294,912
static const size_t OFF_MEM  = 104374272;   // f32 [128 b][128 n][64 m]               = 4,194,304
static const size_t OFF_BAR  = 108568576;   // u32 flags[8 groups][32]: [0..15]=h, [16..31]=r
static const size_t WS_NEED  = 108569600;

// ---------------- prologue kernels ----------------

__global__ void marnn_packw(const float* __restrict__ w_ih, const float* __restrict__ w_hh,
                            const float* __restrict__ b_ih, const float* __restrict__ b_hh,
                            f16* __restrict__ WP, float* __restrict__ biasP) {
  int idx = blockIdx.x * 256 + threadIdx.x;
  if (idx < 2048) {
    int j = idx >> 2, g = idx & 3, rg = g * 512 + j;
    biasP[idx] = b_ih[rg] + b_hh[rg];
  }
  if (idx >= 1703936) return;
  int e = idx & 7, l = (idx >> 3) & 63;
  int q = idx >> 9;
  int ks = q % 26; int ntile = q / 26;
  int n = ntile * 16 + (l & 15);
  int k = ks * 32 + (l >> 4) * 8 + e;
  int j2 = n >> 2, g2 = n & 3, rg2 = g2 * 512 + j2;
  float v = (k < 320) ? w_ih[(size_t)rg2 * 320 + k] : w_hh[(size_t)rg2 * 512 + (k - 320)];
  WP[idx] = (f16)v;
}

// pack embeddings into A-fragment layout, half8-vectorized grid-stride
__global__ void marnn_packemb(const float* __restrict__ embs, f16* __restrict__ embsP) {
  const long total8 = (long)1024 * 128 * 32;
  const long stride = (long)gridDim.x * blockDim.x;
  for (long i8 = (long)blockIdx.x * blockDim.x + threadIdx.x; i8 < total8; i8 += stride) {
    int bl = (int)(i8 & 15), kc = (int)((i8 >> 4) & 31), bg = (int)((i8 >> 9) & 7);
    long t = i8 >> 12;
    const float* s = embs + ((t * 128) + bg * 16 + bl) * 256 + kc * 8;
    f32x4 a = *(const f32x4*)s, b = *(const f32x4*)(s + 4);
    half8 h;
    h[0]=(f16)a[0]; h[1]=(f16)a[1]; h[2]=(f16)a[2]; h[3]=(f16)a[3];
    h[4]=(f16)b[0]; h[5]=(f16)b[1]; h[6]=(f16)b[2]; h[7]=(f16)b[3];
    *(half8*)(embsP + i8 * 8) = h;
  }
}

// precompute v[t][b][m] = emb[t,b] @ W_wv^T + b_wv  (f32, all t), grid-stride
__global__ void marnn_vpre(const float* __restrict__ embs, const float* __restrict__ W_wv,
                           const float* __restrict__ b_wv, float* __restrict__ V) {
  const long total = (long)1024 * 128 * 64;
  const long stride = (long)gridDim.x * blockDim.x;
  for (long idx = (long)blockIdx.x * blockDim.x + threadIdx.x; idx < total; idx += stride) {
    int m = (int)(idx & 63); int b = (int)((idx >> 6) & 127); long t = idx >> 13;
    const float* e = embs + (t * 128 + b) * 256;
    const float* w = W_wv + m * 256;
    float acc = b_wv[m];
    #pragma unroll 4
    for (int k = 0; k < 256; k += 4) {
      f32x4 e4 = *(const f32x4*)(e + k);
      f32x4 w4 = *(const f32x4*)(w + k);
      acc += e4[0]*w4[0] + e4[1]*w4[1] + e4[2]*w4[2] + e4[3]*w4[3];
    }
    V[idx] = acc;
  }
}

__global__ void marnn_init(const float* __restrict__ h0, const float* __restrict__ r0,
                           f16* __restrict__ XPRH) {
  int idx = blockIdx.x * 256 + threadIdx.x;
  if (idx >= 147456) return;
  int e = idx & 7; int q = idx >> 7; int kcidx = q % 72;
  float v = (kcidx < 8) ? r0[kcidx * 8 + e] : h0[(kcidx - 8) * 8 + e];
  XPRH[idx] = (f16)v;
}

// ---------------- main persistent kernel ----------------

struct __align__(16) MarnnSMem {
  f16  whead[128 * 512];   // 131072 B, rotate-swizzled rows
  char xl[26624];          // X frags: [0..8K)=emb/gatebuf, [8K..10K)=r frags, [10K..26K)=h
  char un[4096];           // M scratch: pbuf@0, vpart@512, vred@1536, vsec@3584
};

__device__ __forceinline__ float marnn_dot8(half8 a, half8 b, float acc) {
#if __has_builtin(__builtin_amdgcn_fdot2)
  half2v a0 = {a[0],a[1]}, a1 = {a[2],a[3]}, a2 = {a[4],a[5]}, a3 = {a[6],a[7]};
  half2v b0 = {b[0],b[1]}, b1 = {b[2],b[3]}, b2 = {b[4],b[5]}, b3 = {b[6],b[7]};
  acc = __builtin_amdgcn_fdot2(a0, b0, acc, false);
  acc = __builtin_amdgcn_fdot2(a1, b1, acc, false);
  acc = __builtin_amdgcn_fdot2(a2, b2, acc, false);
  acc = __builtin_amdgcn_fdot2(a3, b3, acc, false);
#else
  #pragma unroll
  for (int e = 0; e < 8; ++e) acc += (float)a[e] * (float)b[e];
#endif
  return acc;
}

__device__ __forceinline__ float fast_sigmoid(float x) {
#if __has_builtin(__builtin_amdgcn_rcpf)
  return __builtin_amdgcn_rcpf(1.f + __expf(-x));
#else
  return 1.f / (1.f + __expf(-x));
#endif
}
__device__ __forceinline__ float fast_tanh(float x) {
#if __has_builtin(__builtin_amdgcn_rcpf)
  return 1.f - 2.f * __builtin_amdgcn_rcpf(1.f + __expf(2.f * x));
#else
  return 1.f - 2.f / (1.f + __expf(2.f * x));
#endif
}

// LLC-coherent primitives: agent-scope relaxed atomics (sc0+sc1, no cache fences)
__device__ __forceinline__ unsigned ld_flag(const unsigned* p) {
  return __hip_atomic_load(p, __ATOMIC_RELAXED, __HIP_MEMORY_SCOPE_AGENT);
}
__device__ __forceinline__ void st_flag(unsigned* p, unsigned v) {
  __hip_atomic_store(p, v, __ATOMIC_RELAXED, __HIP_MEMORY_SCOPE_AGENT);
}
__device__ __forceinline__ u64 ld_llc64(const void* p) {
  return __hip_atomic_load((const u64*)p, __ATOMIC_RELAXED, __HIP_MEMORY_SCOPE_AGENT);
}
__device__ __forceinline__ void st_llc32(void* p, unsigned v) {
  __hip_atomic_store((unsigned*)p, v, __ATOMIC_RELAXED, __HIP_MEMORY_SCOPE_AGENT);
}

// wave-level poll (callers gate to wave 0): lanes 0-15 watch one 64B flag line
__device__ __forceinline__ void poll16(const unsigned* line, unsigned ep) {
  int l = threadIdx.x & 63;
  for (;;) {
    unsigned v = (l < 16) ? ld_flag(line + l) : ep;
    if (__all((int)(v >= ep))) break;
    __builtin_amdgcn_s_sleep(1);
  }
  asm volatile("" ::: "memory");
}

union H2U { f16 f; unsigned short u; };

__global__ __launch_bounds__(512, 1)
void marnn_main(const int* __restrict__ ilen_p, const float* __restrict__ c0,
                const float* __restrict__ r0,
                const float* __restrict__ W_wa, const float* __restrict__ b_wa,
                const float* __restrict__ W_ra, const float* __restrict__ b_ra,
                float* __restrict__ out, char* __restrict__ ws) {
  __shared__ MarnnSMem sm;

  const f16*   WP    = (const f16*)(ws + OFF_WP);
  const float* biasP = (const float*)(ws + OFF_BIAS);
  const f16*   embsP = (const f16*)(ws + OFF_EMBP);
  const float* Vbuf  = (const float*)(ws + OFF_V);
  f16*         XPRH  = (f16*)(ws + OFF_XPRH);
  float*       MEMB  = (float*)(ws + OFF_MEM);
  unsigned*    FLAGS = (unsigned*)(ws + OFF_BAR);

  const int blk = blockIdx.x, tid = threadIdx.x;
  const int wav = tid >> 6, lane = tid & 63;
  // XCD-affine grouping: blocks with equal blk%8 share an XCD under the
  // round-robin dispatch heuristic (perf-only; correctness placement-free)
  const int g = blk & 7, ns = blk >> 3;    // group x n-slice (256 gate rows? no: 32 cols)
  const int ilen = ilen_p[0];
  unsigned* gfh = FLAGS + g * 32;          // h flags, one 64B line
  unsigned* gfr = gfh + 16;                // r flags, next 64B line

  // persistent B-fragments: wave owns n-tile (ns*8 + wav), 16 rows
  half8 bfr[26];
  {
    const f16* wpb = WP + ((size_t)(ns * 8 + wav) * 26) * 512 + lane * 8;
    #pragma unroll
    for (int ks = 0; ks < 26; ++ks) bfr[ks] = *(const half8*)(wpb + ks * 512);
  }

  auto loadWhead = [&](const float* Wsrc) {
    for (int i = tid; i < 8192; i += 512) {
      int n = i >> 6, slot = i & 63;
      const float* s = Wsrc + n * 512 + slot * 8;
      f32x4 a = *(const f32x4*)(s), b2 = *(const f32x4*)(s + 4);
      half8 hv;
      hv[0]=(f16)a[0]; hv[1]=(f16)a[1]; hv[2]=(f16)a[2]; hv[3]=(f16)a[3];
      hv[4]=(f16)b2[0]; hv[5]=(f16)b2[1]; hv[6]=(f16)b2[2]; hv[7]=(f16)b2[3];
      *(half8*)((char*)sm.whead + (n << 10) + (((slot + n) & 63) << 4)) = hv;
    }
  };
  loadWhead(ilen > 0 ? W_wa : W_ra);

  // initial X stage (t=0, parity 0): emb 8KB + h 16KB (plain loads: kernel-boundary coherent)
  {
    const u32x4* s0 = (const u32x4*)(embsP + ((size_t)0 * 8 + g) * 4096);
    ((u32x4*)sm.xl)[tid] = s0[tid];
    const u32x4* s1 = (const u32x4*)(XPRH + (((size_t)0 * 8 + g) * 72 + 8) * 128);
    u32x4* d1 = (u32x4*)(sm.xl + 10240);
    d1[tid * 2] = s1[tid * 2]; d1[tid * 2 + 1] = s1[tid * 2 + 1];
  }
  __syncthreads();

  // activation ownership: thread -> (b_l = tid>>5, jj = tid&31); c in register
  const int b_l = tid >> 5, jj = tid & 31;
  const int jg = ns * 32 + jj;               // j in [0,512)
  float c = c0[jg];
  const f32x4 bias4 = *(const f32x4*)(biasP + ns * 128 + jj * 4);
  const float r0v = (tid < 64) ? r0[tid] : 0.f;
  const int b = g * 16 + ns;                 // this block's memory-head batch

  // M-phase constants: softmax biases (wave 0), GEMV thread mapping
  const float bw0 = b_wa[lane], bw1 = b_wa[lane + 64];
  const float br0 = b_ra[lane], br1 = b_ra[lane + 64];
  const int gn = (wav & 3) * 32 + (lane & 31);   // logit row
  const int kq = ((wav >> 2) << 1) | (lane >> 5); // k-quarter

  // r fragments: constant (=r0) through t <= ilen (regs); then via LDS from wave-0 service
  half8 rf0, rf1;
  {
    const f16* rbase = XPRH + ((size_t)g * 72) * 128 + (lane >> 4) * 128 + (lane & 15) * 8;
    rf0 = *(const half8*)(rbase);
    rf1 = *(const half8*)(rbase + 512);
  }

  for (int t = 0; t < TSTEPS; ++t) {
    const int par = t & 1, nxt = par ^ 1;
    const bool iswrite = (t < ilen);

    // ---- top-of-step prefetches (hide HBM latency under phase A) ----
    u32x4 sa = {0u, 0u, 0u, 0u};
    if (t + 1 < TSTEPS)
      sa = ((const u32x4*)(embsP + (((size_t)(t + 1) * 8) + g) * 4096))[tid];
    f32x4 vv4 = {0.f, 0.f, 0.f, 0.f};
    if (iswrite && wav == 4 && lane < 16)
      vv4 = *(const f32x4*)(Vbuf + ((size_t)t * 128 + b) * 64 + lane * 4);

    // ---------------- phase A: gates GEMM + activations ----------------
    if (t > ilen && wav == 0) {
      // wave 0 services r: poll producer flags, LLC-load, drop into ks8/9 LDS slot
      poll16(gfr, (unsigned)(t - ilen));
      const u64* rp = (const u64*)(XPRH + (((size_t)par * 8 + g) * 72) * 128
                                   + (lane >> 4) * 128 + (lane & 15) * 8);
      union { u64 u[2]; half8 h; } r0u, r1u;
      r0u.u[0] = ld_llc64(rp);       r0u.u[1] = ld_llc64(rp + 1);
      r1u.u[0] = ld_llc64(rp + 128); r1u.u[1] = ld_llc64(rp + 129);
      char* rdst = sm.xl + 8192 + (lane >> 4) * 256 + (lane & 15) * 16;
      *(half8*)rdst = r0u.h;
      *(half8*)(rdst + 1024) = r1u.h;
    }
    f32x4 acc0 = {0.f, 0.f, 0.f, 0.f}, acc1 = {0.f, 0.f, 0.f, 0.f};
    const char* xb = sm.xl + (lane >> 4) * 256 + (lane & 15) * 16;
    #pragma unroll
    for (int ks = 0; ks < 8; ++ks) {
      half8 af = *(const half8*)(xb + ks * 1024);
      if (ks & 1) acc1 = __builtin_amdgcn_mfma_f32_16x16x32_f16(af, bfr[ks], acc1, 0, 0, 0);
      else        acc0 = __builtin_amdgcn_mfma_f32_16x16x32_f16(af, bfr[ks], acc0, 0, 0, 0);
    }
    #pragma unroll
    for (int ks = 10; ks < 26; ++ks) {
      half8 af = *(const half8*)(xb + ks * 1024);
      if (ks & 1) acc1 = __builtin_amdgcn_mfma_f32_16x16x32_f16(af, bfr[ks], acc1, 0, 0, 0);
      else        acc0 = __builtin_amdgcn_mfma_f32_16x16x32_f16(af, bfr[ks], acc0, 0, 0, 0);
    }
    if (t <= ilen) {   // write phase + first read step: r = r0 in registers
      acc0 = __builtin_amdgcn_mfma_f32_16x16x32_f16(rf0, bfr[8], acc0, 0, 0, 0);
      acc1 = __builtin_amdgcn_mfma_f32_16x16x32_f16(rf1, bfr[9], acc1, 0, 0, 0);
    }
    __syncthreads();                         // all waves done reading xl; r frags ready
    if (t > ilen) {
      acc0 = __builtin_amdgcn_mfma_f32_16x16x32_f16(*(const half8*)(xb + 8 * 1024), bfr[8], acc0, 0, 0, 0);
      acc1 = __builtin_amdgcn_mfma_f32_16x16x32_f16(*(const half8*)(xb + 9 * 1024), bfr[9], acc1, 0, 0, 0);
    }
    f32x4 acc = acc0 + acc1;
    {
      float* gatebuf = (float*)sm.xl;        // [16 b][128 n-local] f32 (aliases emb region)
      #pragma unroll
      for (int r = 0; r < 4; ++r)
        gatebuf[((lane >> 4) * 4 + r) * 128 + wav * 16 + (lane & 15)] = acc[r];
    }
    __syncthreads();
    float h;
    {
      const float* gatebuf = (const float*)sm.xl;
      f32x4 g4 = *(const f32x4*)(gatebuf + b_l * 128 + jj * 4);
      float si = fast_sigmoid(g4[0] + bias4[0]);
      float sf = fast_sigmoid(g4[1] + bias4[1]);
      float so = fast_sigmoid(g4[3] + bias4[3]);
      c = sf * c + si * fast_tanh(g4[2] + bias4[2]);
      h = so * fast_tanh(c);
      H2U cv; cv.f = (f16)h;
      int o = __shfl_down((int)cv.u, 1, 64);
      if (!(tid & 1))
        st_llc32(&XPRH[(((size_t)nxt * 8 + g) * 72 + 8 + (jg >> 3)) * 128 + b_l * 8 + (jj & 7)],
                 ((unsigned)cv.u) | (((unsigned)(unsigned short)o) << 16));
    }

    // ---------------- h exchange + X staging for t+1 ----------------
    asm volatile("s_waitcnt vmcnt(0)" ::: "memory");   // h LLC stores acked (per wave)
    __syncthreads();
    if (tid == 0) st_flag(gfh + ns, (unsigned)(t + 1));
    __builtin_nontemporal_store(h, &out[(size_t)t * 73728 + (g * 16 + b_l) * 576 + jg]);
    if (wav == 0) poll16(gfh, (unsigned)(t + 1));
    __syncthreads();
    {
      const u64* s1 = (const u64*)(XPRH + (((size_t)nxt * 8 + g) * 72 + 8) * 128);
      u64 hb0 = ld_llc64(s1 + tid * 4 + 0), hb1 = ld_llc64(s1 + tid * 4 + 1);
      u64 hb2 = ld_llc64(s1 + tid * 4 + 2), hb3 = ld_llc64(s1 + tid * 4 + 3);
      ((u32x4*)sm.xl)[tid] = sa;             // emb_{t+1}
      u64* d1 = (u64*)(sm.xl + 10240);       // h_{t+1}
      d1[tid * 4 + 0] = hb0; d1[tid * 4 + 1] = hb1;
      d1[tid * 4 + 2] = hb2; d1[tid * 4 + 3] = hb3;
    }
    __syncthreads();

    // ---------------- phase M: memory head (each block: batch b) ----------------
    if (t == ilen) { loadWhead(W_ra); __syncthreads(); }
    float* pbuf  = (float*)sm.un;            // 512 B
    float* vpart = (float*)(sm.un + 512);    // 1 KB: [2 kq-pair][128 n]
    float* vred  = (float*)(sm.un + 1536);   // 2 KB
    float* vsec  = (float*)(sm.un + 3584);   // 256 B
    {
      if (iswrite && wav == 4 && lane < 16) *(f32x4*)(vsec + lane * 4) = vv4;
      const char* wrow = (const char*)sm.whead + (gn << 10);
      const char* hbase = sm.xl + 10240 + ns * 16;
      float av0 = 0.f, av1 = 0.f;
      #pragma unroll
      for (int i = 0; i < 16; i += 2) {
        int s0 = kq * 16 + i;
        av0 = marnn_dot8(*(const half8*)(wrow + (((s0 + gn) & 63) << 4)),
                         *(const half8*)(hbase + s0 * 256), av0);
        av1 = marnn_dot8(*(const half8*)(wrow + (((s0 + 1 + gn) & 63) << 4)),
                         *(const half8*)(hbase + (s0 + 1) * 256), av1);
      }
      float av = av0 + av1;
      av += __shfl_xor(av, 32, 64);
      if (lane < 32) vpart[((wav >> 2) << 7) + gn] = av;
    }
    __syncthreads();
    if (wav == 0) {
      float l0 = vpart[lane] + vpart[128 + lane] + (iswrite ? bw0 : br0);
      float l1 = vpart[64 + lane] + vpart[192 + lane] + (iswrite ? bw1 : br1);
      float mx = fmaxf(l0, l1);
      #pragma unroll
      for (int off = 32; off > 0; off >>= 1) mx = fmaxf(mx, __shfl_xor(mx, off, 64));
      float e0 = __expf(l0 - mx), e1 = __expf(l1 - mx);
      float s = e0 + e1;
      #pragma unroll
      for (int off = 32; off > 0; off >>= 1) s += __shfl_xor(s, off, 64);
      float inv = __builtin_amdgcn_rcpf(s);
      pbuf[lane] = e0 * inv; pbuf[lane + 64] = e1 * inv;
    }
    __syncthreads();
    if (iswrite) {
      // mem[b] += wa ⊗ v : thread -> (n = tid>>2, m-quarter = tid&3); L2-resident
      float p = pbuf[tid >> 2];
      float* mrow = MEMB + (((size_t)b) * 128 + (tid >> 2)) * 64 + (tid & 3) * 16;
      const float* vv = vsec + (tid & 3) * 16;
      #pragma unroll
      for (int i2 = 0; i2 < 16; i2 += 4) {
        f32x4 mm = *(f32x4*)(mrow + i2);
        f32x4 v4 = *(const f32x4*)(vv + i2);
        mm = mm + p * v4;
        *(f32x4*)(mrow + i2) = mm;
      }
      if (tid < 64)
        __builtin_nontemporal_store(r0v, &out[(size_t)t * 73728 + b * 576 + 512 + tid]);
    } else {
      // r = ra · mem[b] : thread -> (m = tid&63, n-chunk = wav of 16)
      const int m = tid & 63;
      const float* mcol = MEMB + (((size_t)b) * 128 + wav * 16) * 64 + m;
      float a0 = 0.f, a1 = 0.f;
      #pragma unroll
      for (int n2 = 0; n2 < 16; n2 += 2) {
        a0 = fmaf(pbuf[wav * 16 + n2],     mcol[n2 * 64],       a0);
        a1 = fmaf(pbuf[wav * 16 + n2 + 1], mcol[(n2 + 1) * 64], a1);
      }
      vred[wav * 64 + m] = a0 + a1;
      __syncthreads();
      if (tid < 64) {
        float rv = 0.f;
        #pragma unroll
        for (int nc = 0; nc < 8; ++nc) rv += vred[nc * 64 + tid];
        H2U cr; cr.f = (f16)rv;
        int o2 = __shfl_down((int)cr.u, 1, 64);
        if (!(tid & 1))
          st_llc32(&XPRH[(((size_t)nxt * 8 + g) * 72 + (tid >> 3)) * 128 + ns * 8 + (tid & 7)],
                   ((unsigned)cr.u) | (((unsigned)(unsigned short)o2) << 16));
        asm volatile("s_waitcnt vmcnt(0)" ::: "memory");
        if (tid == 0) st_flag(gfr + ns, (unsigned)(t - ilen + 1));
        __builtin_nontemporal_store(rv, &out[(size_t)t * 73728 + b * 576 + 512 + tid]);
      }
      // no trailing barrier: waves 1-7 run ahead into A_{t+1}; wave 0's r-service
      // and the post-MFMA __syncthreads re-converge the block.
    }
  }
}

// ---------------- host ----------------

extern "C" void kernel_launch(void* const* d_in, const int* in_sizes, int n_in,
                              void* d_out, int out_size, void* d_ws, size_t ws_size,
                              hipStream_t stream) {
  const float* embs = (const float*)d_in[0];
  const int*   ilen = (const int*)d_in[1];
  const float* w_ih = (const float*)d_in[2];
  const float* w_hh = (const float*)d_in[3];
  const float* b_ih = (const float*)d_in[4];
  const float* b_hh = (const float*)d_in[5];
  const float* h0   = (const float*)d_in[6];
  const float* c0   = (const float*)d_in[7];
  const float* r0   = (const float*)d_in[8];
  const float* W_wa = (const float*)d_in[9];
  const float* b_wa = (const float*)d_in[10];
  const float* W_wv = (const float*)d_in[11];
  const float* b_wv = (const float*)d_in[12];
  const float* W_ra = (const float*)d_in[13];
  const float* b_ra = (const float*)d_in[14];
  float* out = (float*)d_out;
  char* ws = (char*)d_ws;
  if (ws_size < WS_NEED) return;  // insufficient scratch: fail cleanly

  hipMemsetAsync(ws + OFF_MEM, 0, 4194304, stream);
  hipMemsetAsync(ws + OFF_BAR, 0, 1024, stream);
  marnn_packw<<<6656, 256, 0, stream>>>(w_ih, w_hh, b_ih, b_hh,
                                        (f16*)(ws + OFF_WP), (float*)(ws + OFF_BIAS));
  marnn_packemb<<<2048, 256, 0, stream>>>(embs, (f16*)(ws + OFF_EMBP));
  marnn_vpre<<<4096, 256, 0, stream>>>(embs, W_wv, b_wv, (float*)(ws + OFF_V));
  marnn_init<<<576, 256, 0, stream>>>(h0, r0, (f16*)(ws + OFF_XPRH));
  marnn_main<<<128, 512, 0, stream>>>(ilen, c0, r0, W_wa, b_wa, W_ra, b_ra, out, ws);
}